// Round 1
// 1001.319 us; speedup vs baseline: 1.2970x; 1.2970x over previous
//
#include <hip/hip_runtime.h>
#include <hip/hip_bf16.h>
#include <float.h>

// Problem constants (from reference setup_inputs)
#define B_   4
#define N_   4096
#define J_   24
#define KR_  4
#define KNN_ 20
#define SLOPE 0.2f
#define SLABN 64             // points per pooling slab
#define NSLAB (N_ / SLABN)   // 64
#define NTILE 32             // 128-wide tiles per dim
#define SCAP 512             // survivor buffer cap (exp. ~60-90 survivors)

// ---------- per-point squared norm ----------
__global__ void k_norm(const float* __restrict__ h, float* __restrict__ xx, int C) {
    int i = blockIdx.x * blockDim.x + threadIdx.x;
    if (i >= B_ * N_) return;
    const float* hp = h + (size_t)i * C;
    float s = 0.f;
    for (int c = 0; c < C; ++c) { float v = hp[c]; s += v * v; }
    xx[i] = s;
}

// ---------- symmetric distance GEMM: upper-tri tiles; grid.y = batch in group ----------
__global__ __launch_bounds__(256) void k_dist(const float* __restrict__ Xall, int C,
                                              const float* __restrict__ xxall,
                                              float* __restrict__ Dall, int b0) {
    __shared__ float As[16][132];
    __shared__ float Bs[16][132];
    int b = b0 + blockIdx.y;
    const float* X   = Xall + (size_t)b * N_ * C;
    const float* xxb = xxall + (size_t)b * N_;
    float* D = Dall + (size_t)blockIdx.y * N_ * N_;

    int t = blockIdx.x;                      // linear upper-tri tile id
    int ti = 0;
    while (t >= NTILE - ti) { t -= NTILE - ti; ++ti; }
    int tj = ti + t;
    int row0 = ti * 128, col0 = tj * 128;
    int tid = threadIdx.x;
    int tr = tid >> 4, tc = tid & 15;
    float acc[8][8] = {{0.f}};
    for (int kt = 0; kt < C; kt += 16) {
#pragma unroll
        for (int i = 0; i < 8; ++i) {
            int e = tid + 256 * i;
            int r = e >> 4, kk = e & 15;
            int gk = kt + kk;
            As[kk][r] = (gk < C) ? X[(size_t)(row0 + r) * C + gk] : 0.f;
            Bs[kk][r] = (gk < C) ? X[(size_t)(col0 + r) * C + gk] : 0.f;
        }
        __syncthreads();
#pragma unroll
        for (int kk = 0; kk < 16; ++kk) {
            float a[8], bv[8];
            *(float4*)&a[0]  = *(const float4*)&As[kk][tr * 4];
            *(float4*)&a[4]  = *(const float4*)&As[kk][64 + tr * 4];
            *(float4*)&bv[0] = *(const float4*)&Bs[kk][tc * 4];
            *(float4*)&bv[4] = *(const float4*)&Bs[kk][64 + tc * 4];
#pragma unroll
            for (int i = 0; i < 8; ++i)
#pragma unroll
                for (int j = 0; j < 8; ++j) acc[i][j] += a[i] * bv[j];
        }
        __syncthreads();
    }
    float xc[8], xr[8];
#pragma unroll
    for (int j = 0; j < 4; ++j) {
        xc[j]     = xxb[col0 + tc * 4 + j];
        xc[4 + j] = xxb[col0 + 64 + tc * 4 + j];
        xr[j]     = xxb[row0 + tr * 4 + j];
        xr[4 + j] = xxb[row0 + 64 + tr * 4 + j];
    }
#pragma unroll
    for (int i = 0; i < 8; ++i) {
        int lr = (i < 4) ? (tr * 4 + i) : (64 + tr * 4 + (i - 4));
        float xri = xr[i];
        float4 o0, o1;
        o0.x = xri + xc[0] - 2.f * acc[i][0];
        o0.y = xri + xc[1] - 2.f * acc[i][1];
        o0.z = xri + xc[2] - 2.f * acc[i][2];
        o0.w = xri + xc[3] - 2.f * acc[i][3];
        o1.x = xri + xc[4] - 2.f * acc[i][4];
        o1.y = xri + xc[5] - 2.f * acc[i][5];
        o1.z = xri + xc[6] - 2.f * acc[i][6];
        o1.w = xri + xc[7] - 2.f * acc[i][7];
        float* dp = D + (size_t)(row0 + lr) * N_ + col0;
        *(float4*)(dp + tc * 4)      = o0;
        *(float4*)(dp + 64 + tc * 4) = o1;
    }
    if (ti == tj) return;
    // mirrored store via LDS transpose, 4 passes of 32 dt-rows
    float* tb = &As[0][0];
    for (int p = 0; p < 4; ++p) {
        __syncthreads();
        int h = p >> 1;
        int tclo = (p & 1) * 8;
        if (tc >= tclo && tc < tclo + 8) {
#pragma unroll
            for (int jj = 0; jj < 4; ++jj) {
                int j = h * 4 + jj;
                int cl = h * 64 + tc * 4 + jj - 32 * p;   // 0..31
                float xcj = xc[j];
                float4 vlo, vhi;
                vlo.x = xr[0] + xcj - 2.f * acc[0][j];
                vlo.y = xr[1] + xcj - 2.f * acc[1][j];
                vlo.z = xr[2] + xcj - 2.f * acc[2][j];
                vlo.w = xr[3] + xcj - 2.f * acc[3][j];
                vhi.x = xr[4] + xcj - 2.f * acc[4][j];
                vhi.y = xr[5] + xcj - 2.f * acc[5][j];
                vhi.z = xr[6] + xcj - 2.f * acc[6][j];
                vhi.w = xr[7] + xcj - 2.f * acc[7][j];
                *(float4*)&tb[cl * 132 + tr * 4]      = vlo;
                *(float4*)&tb[cl * 132 + 64 + tr * 4] = vhi;
            }
        }
        __syncthreads();
        int rl  = tid >> 3;
        int c16 = (tid & 7) * 16;
#pragma unroll
        for (int q = 0; q < 4; ++q) {
            float4 v = *(const float4*)&tb[rl * 132 + c16 + q * 4];
            *(float4*)(D + (size_t)(col0 + 32 * p + rl) * N_ + row0 + c16 + q * 4) = v;
        }
    }
}

// ---------- key mapping: monotone f32 -> u32 ----------
__device__ __forceinline__ unsigned mapf(float f) {
    unsigned u = __float_as_uint(f);
    return (u & 0x80000000u) ? ~u : (u | 0x80000000u);
}

// ---------- 64-lane butterfly helpers ----------
__device__ __forceinline__ unsigned long long shflx64(unsigned long long v, int m) {
    unsigned lo = (unsigned)v, hi = (unsigned)(v >> 32);
    lo = (unsigned)__shfl_xor((int)lo, m, 64);
    hi = (unsigned)__shfl_xor((int)hi, m, 64);
    return ((unsigned long long)hi << 32) | lo;
}

// full ascending bitonic sort of one f32 per lane across the wave
__device__ __forceinline__ float bsort64f(float v, int lane) {
#pragma unroll
    for (int k = 2; k <= 64; k <<= 1) {
#pragma unroll
        for (int j = k >> 1; j > 0; j >>= 1) {
            float o = __shfl_xor(v, j, 64);
            bool keepmin = (((lane & j) == 0) == ((lane & k) == 0));
            float mn = fminf(v, o), mx = fmaxf(v, o);
            v = keepmin ? mn : mx;
        }
    }
    return v;
}

// full ascending bitonic sort of one u64 key per lane across the wave
__device__ __forceinline__ unsigned long long bsort64u(unsigned long long v, int lane) {
#pragma unroll
    for (int k = 2; k <= 64; k <<= 1) {
#pragma unroll
        for (int j = k >> 1; j > 0; j >>= 1) {
            unsigned long long o = shflx64(v, j);
            bool keepmin = (((lane & j) == 0) == ((lane & k) == 0));
            bool oless = o < v;
            unsigned long long mn = oless ? o : v;
            unsigned long long mx = oless ? v : o;
            v = keepmin ? mn : mx;
        }
    }
    return v;
}

// ---------- top-20 via threshold filter + survivor compaction + bitonic ----------
// tau = min over waves of (20th-smallest of 64 lane-mins) is a provable upper
// bound on the true 20th-smallest distance of the row: the 20 smallest
// lane-mins are 20 distinct data values <= tau. Filtering v <= tau therefore
// keeps an exact superset of the top-20 (ties included); a u64 bitonic over
// (mapped_value, index) keys yields the exact, tie-stable result.
__global__ __launch_bounds__(256) void k_sel(const float* __restrict__ Dall,
                                             int* __restrict__ knnIdx, int b0) {
    __shared__ unsigned long long sbuf[SCAP];
    __shared__ float stau[4];
    __shared__ int scnt;
    const float* Db = Dall + (size_t)blockIdx.y * N_ * N_;
    int* idxout = knnIdx + (size_t)(b0 + blockIdx.y) * N_ * KNN_;
    int ql   = blockIdx.x;
    int wv   = threadIdx.x >> 6;
    int lane = threadIdx.x & 63;
    int gbase = wv * 1024 + lane * 16;
    const float* seg = Db + (size_t)ql * N_ + gbase;
    if (threadIdx.x == 0) scnt = 0;

    float4 v4[4];
    v4[0] = *(const float4*)(seg);
    v4[1] = *(const float4*)(seg + 4);
    v4[2] = *(const float4*)(seg + 8);
    v4[3] = *(const float4*)(seg + 12);
    const float* vv = (const float*)v4;

    float mn = vv[0];
#pragma unroll
    for (int t = 1; t < 16; ++t) mn = fminf(mn, vv[t]);
    mn = bsort64f(mn, lane);
    float tw = __shfl(mn, 19, 64);
    if (lane == 0) stau[wv] = tw;
    __syncthreads();
    float tau = fminf(fminf(stau[0], stau[1]), fminf(stau[2], stau[3]));

#pragma unroll
    for (int t = 0; t < 16; ++t) {
        if (vv[t] <= tau) {
            int p = atomicAdd(&scnt, 1);
            if (p < SCAP)
                sbuf[p] = ((unsigned long long)mapf(vv[t]) << 32) | (unsigned)(gbase + t);
        }
    }
    __syncthreads();
    if (wv != 0) return;
    int S = scnt; if (S > SCAP) S = SCAP;
    unsigned long long key = (lane < S) ? sbuf[lane] : ~0ull;
    key = bsort64u(key, lane);
    for (int consumed = 64; consumed < S; consumed += 44) {
        if (lane >= 20) {
            int src = consumed + lane - 20;
            key = (src < S) ? sbuf[src] : ~0ull;
        }
        key = bsort64u(key, lane);
    }
    if (lane < KNN_) idxout[ql * KNN_ + lane] = (int)(unsigned)key;
}

// ---------- layer-1 fused dist+select (C=3), same selection scheme ----------
__global__ __launch_bounds__(256) void k_selC3(const float* __restrict__ V,
                                               const float* __restrict__ xx,
                                               int* __restrict__ knnIdx) {
    __shared__ unsigned long long sbuf[SCAP];
    __shared__ float stau[4];
    __shared__ int scnt;
    int b    = blockIdx.y;
    const float* Xb  = V + (size_t)b * N_ * 3;
    const float* xxb = xx + (size_t)b * N_;
    int* idxout = knnIdx + (size_t)b * N_ * KNN_;
    int q    = blockIdx.x;
    int wv   = threadIdx.x >> 6;
    int lane = threadIdx.x & 63;
    int gbase = wv * 1024 + lane * 16;
    if (threadIdx.x == 0) scnt = 0;

    float qx = Xb[q * 3], qy = Xb[q * 3 + 1], qz = Xb[q * 3 + 2];
    float xxq = xxb[q];

    float pts[48];
    const float4* src = (const float4*)(Xb + (size_t)gbase * 3);
#pragma unroll
    for (int t = 0; t < 12; ++t) ((float4*)pts)[t] = src[t];

    float dv[16];
#pragma unroll
    for (int t = 0; t < 16; ++t) {
        float dot = qx * pts[3 * t];
        dot = fmaf(qy, pts[3 * t + 1], dot);
        dot = fmaf(qz, pts[3 * t + 2], dot);
        dv[t] = xxq + xxb[gbase + t] - 2.f * dot;
    }

    float mn = dv[0];
#pragma unroll
    for (int t = 1; t < 16; ++t) mn = fminf(mn, dv[t]);
    mn = bsort64f(mn, lane);
    float tw = __shfl(mn, 19, 64);
    if (lane == 0) stau[wv] = tw;
    __syncthreads();
    float tau = fminf(fminf(stau[0], stau[1]), fminf(stau[2], stau[3]));

#pragma unroll
    for (int t = 0; t < 16; ++t) {
        if (dv[t] <= tau) {
            int p = atomicAdd(&scnt, 1);
            if (p < SCAP)
                sbuf[p] = ((unsigned long long)mapf(dv[t]) << 32) | (unsigned)(gbase + t);
        }
    }
    __syncthreads();
    if (wv != 0) return;
    int S = scnt; if (S > SCAP) S = SCAP;
    unsigned long long key = (lane < S) ? sbuf[lane] : ~0ull;
    key = bsort64u(key, lane);
    for (int consumed = 64; consumed < S; consumed += 44) {
        if (lane >= 20) {
            int srci = consumed + lane - 20;
            key = (srci < S) ? sbuf[srci] : ~0ull;
        }
        key = bsort64u(key, lane);
    }
    if (lane < KNN_) idxout[q * KNN_ + lane] = (int)(unsigned)key;
}

// ---------- fused weight prep ----------
__device__ __forceinline__ void prepP_elem(const float* __restrict__ w,
                                           const float* __restrict__ bias,
                                           int C, int O, float* __restrict__ P,
                                           float* __restrict__ b2, int i) {
    int O2 = 2 * O;
    if (i < O2) b2[i] = (i < O) ? 0.f : bias[i - O];
    if (i >= C * O2) return;
    int k = i / O2, col = i % O2;
    float v;
    if (col < O) v = w[(size_t)col * 2 * C + k];
    else { int o = col - O; v = w[(size_t)o * 2 * C + C + k] - w[(size_t)o * 2 * C + k]; }
    P[i] = v;
}
__device__ __forceinline__ void transp_elem(const float* __restrict__ w, int O, int K,
                                            float* __restrict__ wT, int i) {
    if (i >= O * K) return;
    int k = i / O, o = i % O;
    wT[i] = w[(size_t)o * K + k];
}

__global__ void k_prepall(const float* g1w, const float* g1b,
                          const float* g2w, const float* g2b,
                          const float* g3w, const float* g3b,
                          const float* s1w, const float* s1b,
                          const float* s2w, const float* s2b,
                          const float* s3w, const float* s3b,
                          const float* m1w, const float* m2w, const float* m3w,
                          float* P1, float* P2, float* P3, float* P4, float* P5,
                          float* P6, float* P7, float* P8, float* P9,
                          float* bb1, float* bb2, float* bb3,
                          float* bb4, float* bb5, float* bb6) {
    int i = blockIdx.x * 256 + threadIdx.x;
    switch (blockIdx.y) {
        case 0: prepP_elem(g1w, g1b, 3,   64,  P1, bb1, i); break;
        case 1: prepP_elem(g2w, g2b, 64,  128, P2, bb2, i); break;
        case 2: prepP_elem(g3w, g3b, 128, 256, P3, bb3, i); break;
        case 3: prepP_elem(s1w, s1b, 451, 256, P4, bb4, i); break;
        case 4: prepP_elem(s2w, s2b, 256, 128, P5, bb5, i); break;
        case 5: prepP_elem(s3w, s3b, 128, 64,  P6, bb6, i); break;
        case 6: transp_elem(m1w, 512, 448, P7, i); break;
        case 7: transp_elem(m2w, 256, 512, P8, i); break;
        case 8: transp_elem(m3w, 3,   256, P9, i); break;
    }
}

// ---------- tiled f32 GEMM (large M) ----------
__global__ __launch_bounds__(256) void k_gemm(const float* __restrict__ A, int lda,
                                              const float* __restrict__ Bm,
                                              float* __restrict__ Cm, int ldc,
                                              int M, int N, int K,
                                              const float* __restrict__ bias, int leaky) {
    __shared__ float As[16][68];
    __shared__ float Bs[16][68];
    int tid = threadIdx.x;
    int row0 = blockIdx.y * 64, col0 = blockIdx.x * 64;
    int tr = tid >> 4, tc = tid & 15;
    float acc[4][4] = {{0.f}};
    for (int kt = 0; kt < K; kt += 16) {
#pragma unroll
        for (int i = 0; i < 4; ++i) {
            int e = tid + 256 * i;
            int r = e >> 4, kk = e & 15;
            int gr = row0 + r, gk = kt + kk;
            float v = 0.f;
            if (gr < M && gk < K) v = A[(size_t)gr * lda + gk];
            As[kk][r] = v;
        }
#pragma unroll
        for (int i = 0; i < 4; ++i) {
            int e = tid + 256 * i;
            int kk = e >> 6, c = e & 63;
            int gk = kt + kk, gc = col0 + c;
            float v = 0.f;
            if (gk < K && gc < N) v = Bm[(size_t)gk * N + gc];
            Bs[kk][c] = v;
        }
        __syncthreads();
#pragma unroll
        for (int kk = 0; kk < 16; ++kk) {
            float a[4], bv[4];
            *(float4*)&a[0]  = *(const float4*)&As[kk][tr * 4];
            *(float4*)&bv[0] = *(const float4*)&Bs[kk][tc * 4];
#pragma unroll
            for (int i = 0; i < 4; ++i)
#pragma unroll
                for (int j = 0; j < 4; ++j) acc[i][j] += a[i] * bv[j];
        }
        __syncthreads();
    }
#pragma unroll
    for (int i = 0; i < 4; ++i) {
        int r = row0 + tr * 4 + i;
        if (r >= M) continue;
#pragma unroll
        for (int j = 0; j < 4; ++j) {
            int c = col0 + tc * 4 + j;
            if (c >= N) continue;
            float v = acc[i][j];
            if (bias) v += bias[c];
            if (leaky) v = v >= 0.f ? v : SLOPE * v;
            Cm[(size_t)r * ldc + c] = v;
        }
    }
}

// ---------- small-M GEMM ----------
__global__ __launch_bounds__(256) void k_sgemm(const float* __restrict__ A, int lda,
                                               const float* __restrict__ Bm,
                                               float* __restrict__ Cm, int ldc,
                                               int N, int K,
                                               const float* __restrict__ bias, int leaky) {
    extern __shared__ float Arow[];
    int r   = blockIdx.x;
    int c0  = blockIdx.y * 256;
    int tid = threadIdx.x;
    for (int k = tid; k < K; k += 256) Arow[k] = A[(size_t)r * lda + k];
    __syncthreads();
    int c = c0 + tid;
    if (c >= N) return;
    float acc = bias ? bias[c] : 0.f;
    for (int k = 0; k < K; ++k) acc += Arow[k] * Bm[(size_t)k * N + c];
    if (leaky) acc = acc >= 0.f ? acc : SLOPE * acc;
    Cm[(size_t)r * ldc + c] = acc;
}

// ---------- gather-max epilogue (+ optional fused row-norm) ----------
__global__ void k_gathermax(const float* __restrict__ Y, int O, int R,
                            const int* __restrict__ idx, int kc,
                            float* __restrict__ out, int ldo, int ooff,
                            float* __restrict__ xxout) {
    extern __shared__ int sidx[];
    __shared__ float red[256];
    int br = blockIdx.x;
    int b  = br / R;
    int o  = threadIdx.x;
    if (o < kc) sidx[o] = idx[(size_t)br * kc + o];
    __syncthreads();
    int O2 = 2 * O;
    float z = Y[(size_t)br * O2 + O + o];
    float best = -FLT_MAX;
    for (int k = 0; k < kc; ++k) {
        int m = sidx[k];
        best = fmaxf(best, Y[(size_t)(b * R + m) * O2 + o]);
    }
    float r = z + best;
    r = r >= 0.f ? r : SLOPE * r;
    out[(size_t)br * ldo + ooff + o] = r;
    if (xxout) {
        red[o] = r * r;
        __syncthreads();
        for (int s = blockDim.x >> 1; s > 0; s >>= 1) {
            if (o < s) red[o] += red[o + s];
            __syncthreads();
        }
        if (o == 0) xxout[br] = red[0];
    }
}

// ---------- channel map ----------
__device__ __forceinline__ void chan_map(int b, int c,
                                         const float* Vf, const float* l1,
                                         const float* l2, const float* l3,
                                         const float*& p, int& st) {
    if (c < 3)        { st = 3;   p = Vf + (size_t)b * N_ * 3   + c; }
    else if (c < 67)  { st = 64;  p = l1 + (size_t)b * N_ * 64  + (c - 3); }
    else if (c < 195) { st = 128; p = l2 + (size_t)b * N_ * 128 + (c - 67); }
    else              { st = 256; p = l3 + (size_t)b * N_ * 256 + (c - 195); }
}

// ---------- pooling phase 1 ----------
__global__ __launch_bounds__(256) void k_pool2(const float* __restrict__ Vf,
                                               const float* __restrict__ l1,
                                               const float* __restrict__ l2,
                                               const float* __restrict__ l3,
                                               const float* __restrict__ W,
                                               float* __restrict__ ppool,
                                               float* __restrict__ psw) {
    __shared__ float Wl[SLABN][J_];
    int blk  = blockIdx.x;
    int b    = blk / NSLAB, slab = blk % NSLAB;
    int n0   = slab * SLABN;
    int tid  = threadIdx.x;

    for (int e = tid; e < J_ * SLABN; e += 256) {
        int j = e / SLABN, n = e % SLABN;
        Wl[n][j] = W[((size_t)b * J_ + j) * N_ + n0 + n];
    }
    __syncthreads();

    if (tid < J_) {
        float s = 0.f;
        for (int n = 0; n < SLABN; ++n) s += Wl[n][tid];
        psw[(size_t)blk * J_ + tid] = s;
    }

    int c0 = tid, c1 = tid + 256;
    const float *p0, *p1 = nullptr; int s0, s1 = 0;
    chan_map(b, c0, Vf, l1, l2, l3, p0, s0);
    bool has1 = (c1 < 451);
    if (has1) chan_map(b, c1, Vf, l1, l2, l3, p1, s1);

    float acc0[J_], acc1[J_];
#pragma unroll
    for (int j = 0; j < J_; ++j) { acc0[j] = 0.f; acc1[j] = 0.f; }

    for (int n = 0; n < SLABN; ++n) {
        float v0 = p0[(size_t)(n0 + n) * s0];
        float v1 = has1 ? p1[(size_t)(n0 + n) * s1] : 0.f;
        const float* wn = &Wl[n][0];
#pragma unroll
        for (int q = 0; q < J_ / 4; ++q) {
            float4 w4 = *(const float4*)(wn + 4 * q);
            acc0[4*q+0] += w4.x * v0;  acc1[4*q+0] += w4.x * v1;
            acc0[4*q+1] += w4.y * v0;  acc1[4*q+1] += w4.y * v1;
            acc0[4*q+2] += w4.z * v0;  acc1[4*q+2] += w4.z * v1;
            acc0[4*q+3] += w4.w * v0;  acc1[4*q+3] += w4.w * v1;
        }
    }
    float* pp = ppool + (size_t)blk * J_ * 451;
#pragma unroll
    for (int j = 0; j < J_; ++j) {
        pp[(size_t)j * 451 + c0] = acc0[j];
        if (has1) pp[(size_t)j * 451 + c1] = acc1[j];
    }
}

// ---------- pooling phase 2 ----------
__global__ __launch_bounds__(256) void k_poolred(const float* __restrict__ ppool,
                                                 const float* __restrict__ psw,
                                                 float* __restrict__ pooled) {
    int bj = blockIdx.x;
    int b  = bj / J_, j = bj % J_;
    int tid = threadIdx.x;

    float sw = 0.f;
    for (int sl = 0; sl < NSLAB; ++sl) sw += psw[(size_t)(b * NSLAB + sl) * J_ + j];
    float inv = 1.f / (sw + 1e-5f);

    for (int c = tid; c < 451; c += 256) {
        float s = 0.f;
        for (int sl = 0; sl < NSLAB; ++sl)
            s += ppool[((size_t)(b * NSLAB + sl) * J_ + j) * 451 + c];
        pooled[(size_t)bj * 451 + c] = s * inv;
    }
}

extern "C" void kernel_launch(void* const* d_in, const int* in_sizes, int n_in,
                              void* d_out, int out_size, void* d_ws, size_t ws_size,
                              hipStream_t stream) {
    const float* V  = (const float*)d_in[0];
    const float* W  = (const float*)d_in[1];
    const int* ringIdx = (const int*)d_in[2];
    const float* g1w = (const float*)d_in[3];
    const float* g1b = (const float*)d_in[4];
    const float* g2w = (const float*)d_in[5];
    const float* g2b = (const float*)d_in[6];
    const float* g3w = (const float*)d_in[7];
    const float* g3b = (const float*)d_in[8];
    const float* s1w = (const float*)d_in[9];
    const float* s1b = (const float*)d_in[10];
    const float* s2w = (const float*)d_in[11];
    const float* s2b = (const float*)d_in[12];
    const float* s3w = (const float*)d_in[13];
    const float* s3b = (const float*)d_in[14];
    const float* m1w = (const float*)d_in[15];
    const float* m1b = (const float*)d_in[16];
    const float* m2w = (const float*)d_in[17];
    const float* m2b = (const float*)d_in[18];
    const float* m3w = (const float*)d_in[19];
    const float* m3b = (const float*)d_in[20];
    (void)n_in; (void)in_sizes; (void)out_size;

    const int szP1 = 3 * 128,    szP2 = 64 * 256,  szP3 = 128 * 512;
    const int szP4 = 451 * 512,  szP5 = 256 * 256, szP6 = 128 * 128;
    const int szP7 = 448 * 512,  szP8 = 512 * 256, szP9 = 256 * 3;

    // ---- bytes needed for nd D-buffers (rest of layout fixed) ----
    auto layout_bytes = [&](int nd) -> size_t {
        size_t f = 0;
        f += (size_t)B_ * N_ * 64 + (size_t)B_ * N_ * 128 + (size_t)B_ * N_ * 256;
        f += (size_t)B_ * N_;                         // xx
        f += (size_t)nd * N_ * N_;                    // D buffers
        f += (size_t)B_ * N_ * KNN_;                  // knnIdx (ints)
        f += (size_t)B_ * J_ * 451 + (size_t)B_ * J_ * 448;
        f += (size_t)B_ * J_ * 512 + (size_t)B_ * J_ * 256;
        f += (size_t)(szP1 + szP2 + szP3 + szP4 + szP5 + szP6 + szP7 + szP8 + szP9);
        f += 128 + 256 + 512 + 512 + 256 + 128;
        return f * 4;
    };
    // nb = batches per dist/sel group (deterministic in ws_size -> graph-safe)
    int nb = 1;
    if (ws_size >= layout_bytes(4)) nb = 4;
    else if (ws_size >= layout_bytes(2)) nb = 2;

    // ---- workspace layout (floats) ----
    float* ws = (float*)d_ws;
    size_t off = 0;
    float* l1 = ws + off; off += (size_t)B_ * N_ * 64;
    float* l2 = ws + off; off += (size_t)B_ * N_ * 128;
    float* l3 = ws + off; off += (size_t)B_ * N_ * 256;
    float* xx = ws + off; off += (size_t)B_ * N_;
    float* D  = ws + off; off += (size_t)nb * N_ * N_;   // nb D buffers
    float* Y  = D;                                        // 32 MB <= first D buffer
    float* ppool = D;
    float* psw   = D + (size_t)B_ * NSLAB * J_ * 451;
    int* knnIdx = (int*)(ws + off); off += (size_t)B_ * N_ * KNN_;
    float* pooled = ws + off; off += (size_t)B_ * J_ * 451;
    float* joints = ws + off; off += (size_t)B_ * J_ * 448;
    float* h1 = ws + off; off += (size_t)B_ * J_ * 512;
    float* h2 = ws + off; off += (size_t)B_ * J_ * 256;
    float* P1 = ws + off; off += szP1;
    float* P2 = ws + off; off += szP2;
    float* P3 = ws + off; off += szP3;
    float* P4 = ws + off; off += szP4;
    float* P5 = ws + off; off += szP5;
    float* P6 = ws + off; off += szP6;
    float* P7 = ws + off; off += szP7;
    float* P8 = ws + off; off += szP8;
    float* P9 = ws + off; off += szP9;
    float* bb1 = ws + off; off += 128;
    float* bb2 = ws + off; off += 256;
    float* bb3 = ws + off; off += 512;
    float* bb4 = ws + off; off += 512;
    float* bb5 = ws + off; off += 256;
    float* bb6 = ws + off; off += 128;

    const int M = B_ * N_;   // 16384
    const int MJ = B_ * J_;  // 96
    const int NUTRI = NTILE * (NTILE + 1) / 2;   // 528 upper-tri tiles

    // ---- all weight prep in one launch ----
    k_prepall<<<dim3((szP4 + 255) / 256, 9), 256, 0, stream>>>(
        g1w, g1b, g2w, g2b, g3w, g3b, s1w, s1b, s2w, s2b, s3w, s3b,
        m1w, m2w, m3w, P1, P2, P3, P4, P5, P6, P7, P8, P9,
        bb1, bb2, bb3, bb4, bb5, bb6);

    // ======== geoNet layer 1: C=3 -> O=64 (fused dist+select) ========
    k_norm<<<(M + 255) / 256, 256, 0, stream>>>(V, xx, 3);
    k_selC3<<<dim3(N_, B_), 256, 0, stream>>>(V, xx, knnIdx);
    k_gemm<<<dim3(2, M / 64), 256, 0, stream>>>(V, 3, P1, Y, 128, M, 128, 3, bb1, 0);
    k_gathermax<<<M, 64, KNN_ * sizeof(int), stream>>>(Y, 64, N_, knnIdx, KNN_, l1, 64, 0, xx);

    // ======== layer 2: C=64 -> O=128 ========
    for (int g = 0; g < B_; g += nb) {
        k_dist<<<dim3(NUTRI, nb), 256, 0, stream>>>(l1, 64, xx, D, g);
        k_sel<<<dim3(N_, nb), 256, 0, stream>>>(D, knnIdx, g);
    }
    k_gemm<<<dim3(4, M / 64), 256, 0, stream>>>(l1, 64, P2, Y, 256, M, 256, 64, bb2, 0);
    k_gathermax<<<M, 128, KNN_ * sizeof(int), stream>>>(Y, 128, N_, knnIdx, KNN_, l2, 128, 0, xx);

    // ======== layer 3: C=128 -> O=256 ========
    for (int g = 0; g < B_; g += nb) {
        k_dist<<<dim3(NUTRI, nb), 256, 0, stream>>>(l2, 128, xx, D, g);
        k_sel<<<dim3(N_, nb), 256, 0, stream>>>(D, knnIdx, g);
    }
    k_gemm<<<dim3(8, M / 64), 256, 0, stream>>>(l2, 128, P3, Y, 512, M, 512, 128, bb3, 0);
    k_gathermax<<<M, 256, KNN_ * sizeof(int), stream>>>(Y, 256, N_, knnIdx, KNN_, l3, 256, 0, nullptr);

    // ======== pooling onto joints ========
    k_pool2<<<B_ * NSLAB, 256, 0, stream>>>(V, l1, l2, l3, W, ppool, psw);
    k_poolred<<<MJ, 256, 0, stream>>>(ppool, psw, pooled);

    // ======== skeleton convs ========
    k_sgemm<<<dim3(MJ, 2), 256, 451 * sizeof(float), stream>>>(pooled, 451, P4, Y, 512, 512, 451, bb4, 0);
    k_gathermax<<<MJ, 256, KR_ * sizeof(int), stream>>>(Y, 256, J_, ringIdx, KR_, joints, 448, 0, nullptr);

    k_sgemm<<<dim3(MJ, 1), 256, 256 * sizeof(float), stream>>>(joints, 448, P5, Y, 256, 256, 256, bb5, 0);
    k_gathermax<<<MJ, 128, KR_ * sizeof(int), stream>>>(Y, 128, J_, ringIdx, KR_, joints, 448, 256, nullptr);

    k_sgemm<<<dim3(MJ, 1), 256, 128 * sizeof(float), stream>>>(joints + 256, 448, P6, Y, 128, 128, 128, bb6, 0);
    k_gathermax<<<MJ, 64, KR_ * sizeof(int), stream>>>(Y, 64, J_, ringIdx, KR_, joints, 448, 384, nullptr);

    // ======== joint MLP ========
    k_sgemm<<<dim3(MJ, 2), 256, 448 * sizeof(float), stream>>>(joints, 448, P7, h1, 512, 512, 448, m1b, 1);
    k_sgemm<<<dim3(MJ, 1), 256, 512 * sizeof(float), stream>>>(h1, 512, P8, h2, 256, 256, 512, m2b, 1);
    k_sgemm<<<dim3(MJ, 1), 256, 256 * sizeof(float), stream>>>(h2, 256, P9, (float*)d_out, 3, 3, 256, m3b, 0);
}

// Round 2
// 995.844 us; speedup vs baseline: 1.3041x; 1.0055x over previous
//
#include <hip/hip_runtime.h>
#include <hip/hip_bf16.h>
#include <float.h>

// Problem constants (from reference setup_inputs)
#define B_   4
#define N_   4096
#define J_   24
#define KR_  4
#define KNN_ 20
#define SLOPE 0.2f
#define SLABN 64             // points per pooling slab
#define NSLAB (N_ / SLABN)   // 64
#define NTILE 32             // 128-wide tiles per dim
#define SCAP 512             // survivor buffer cap (exp. ~60-100 survivors)

// ---------- per-point squared norm ----------
__global__ void k_norm(const float* __restrict__ h, float* __restrict__ xx, int C) {
    int i = blockIdx.x * blockDim.x + threadIdx.x;
    if (i >= B_ * N_) return;
    const float* hp = h + (size_t)i * C;
    float s = 0.f;
    for (int c = 0; c < C; ++c) { float v = hp[c]; s += v * v; }
    xx[i] = s;
}

// ---------- monotone key maps ----------
__device__ __forceinline__ unsigned mapf(float f) {
    unsigned u = __float_as_uint(f);
    return (u & 0x80000000u) ? ~u : (u | 0x80000000u);
}
// top-16 bits of mapf: monotone f32 -> u16 (truncation preserves order)
__device__ __forceinline__ unsigned key16(float f) {
    return mapf(f) >> 16;
}

// ---------- symmetric distance GEMM -> u16 keys; upper-tri tiles; grid.y = batch ----------
__global__ __launch_bounds__(256) void k_dist(const float* __restrict__ Xall, int C,
                                              const float* __restrict__ xxall,
                                              unsigned short* __restrict__ Dall, int b0) {
    __shared__ float As[16][132];
    __shared__ float Bs[16][132];
    int b = b0 + blockIdx.y;
    const float* X   = Xall + (size_t)b * N_ * C;
    const float* xxb = xxall + (size_t)b * N_;
    unsigned short* D = Dall + (size_t)blockIdx.y * N_ * N_;

    int t = blockIdx.x;                      // linear upper-tri tile id
    int ti = 0;
    while (t >= NTILE - ti) { t -= NTILE - ti; ++ti; }
    int tj = ti + t;
    int row0 = ti * 128, col0 = tj * 128;
    int tid = threadIdx.x;
    int tr = tid >> 4, tc = tid & 15;
    float acc[8][8] = {{0.f}};
    for (int kt = 0; kt < C; kt += 16) {
#pragma unroll
        for (int i = 0; i < 8; ++i) {
            int e = tid + 256 * i;
            int r = e >> 4, kk = e & 15;
            int gk = kt + kk;
            As[kk][r] = (gk < C) ? X[(size_t)(row0 + r) * C + gk] : 0.f;
            Bs[kk][r] = (gk < C) ? X[(size_t)(col0 + r) * C + gk] : 0.f;
        }
        __syncthreads();
#pragma unroll
        for (int kk = 0; kk < 16; ++kk) {
            float a[8], bv[8];
            *(float4*)&a[0]  = *(const float4*)&As[kk][tr * 4];
            *(float4*)&a[4]  = *(const float4*)&As[kk][64 + tr * 4];
            *(float4*)&bv[0] = *(const float4*)&Bs[kk][tc * 4];
            *(float4*)&bv[4] = *(const float4*)&Bs[kk][64 + tc * 4];
#pragma unroll
            for (int i = 0; i < 8; ++i)
#pragma unroll
                for (int j = 0; j < 8; ++j) acc[i][j] += a[i] * bv[j];
        }
        __syncthreads();
    }
    float xc[8], xr[8];
#pragma unroll
    for (int j = 0; j < 4; ++j) {
        xc[j]     = xxb[col0 + tc * 4 + j];
        xc[4 + j] = xxb[col0 + 64 + tc * 4 + j];
        xr[j]     = xxb[row0 + tr * 4 + j];
        xr[4 + j] = xxb[row0 + 64 + tr * 4 + j];
    }
#pragma unroll
    for (int i = 0; i < 8; ++i) {
        int lr = (i < 4) ? (tr * 4 + i) : (64 + tr * 4 + (i - 4));
        float xri = xr[i];
        float o0x = xri + xc[0] - 2.f * acc[i][0];
        float o0y = xri + xc[1] - 2.f * acc[i][1];
        float o0z = xri + xc[2] - 2.f * acc[i][2];
        float o0w = xri + xc[3] - 2.f * acc[i][3];
        float o1x = xri + xc[4] - 2.f * acc[i][4];
        float o1y = xri + xc[5] - 2.f * acc[i][5];
        float o1z = xri + xc[6] - 2.f * acc[i][6];
        float o1w = xri + xc[7] - 2.f * acc[i][7];
        unsigned short* dp = D + (size_t)(row0 + lr) * N_ + col0;
        uint2 w0, w1;
        w0.x = key16(o0x) | (key16(o0y) << 16);
        w0.y = key16(o0z) | (key16(o0w) << 16);
        w1.x = key16(o1x) | (key16(o1y) << 16);
        w1.y = key16(o1z) | (key16(o1w) << 16);
        *(uint2*)(dp + tc * 4)      = w0;
        *(uint2*)(dp + 64 + tc * 4) = w1;
    }
    if (ti == tj) return;
    // mirrored store via LDS transpose (f32), convert to keys at global store
    float* tb = &As[0][0];
    for (int p = 0; p < 4; ++p) {
        __syncthreads();
        int h = p >> 1;
        int tclo = (p & 1) * 8;
        if (tc >= tclo && tc < tclo + 8) {
#pragma unroll
            for (int jj = 0; jj < 4; ++jj) {
                int j = h * 4 + jj;
                int cl = h * 64 + tc * 4 + jj - 32 * p;   // 0..31
                float xcj = xc[j];
                float4 vlo, vhi;
                vlo.x = xr[0] + xcj - 2.f * acc[0][j];
                vlo.y = xr[1] + xcj - 2.f * acc[1][j];
                vlo.z = xr[2] + xcj - 2.f * acc[2][j];
                vlo.w = xr[3] + xcj - 2.f * acc[3][j];
                vhi.x = xr[4] + xcj - 2.f * acc[4][j];
                vhi.y = xr[5] + xcj - 2.f * acc[5][j];
                vhi.z = xr[6] + xcj - 2.f * acc[6][j];
                vhi.w = xr[7] + xcj - 2.f * acc[7][j];
                *(float4*)&tb[cl * 132 + tr * 4]      = vlo;
                *(float4*)&tb[cl * 132 + 64 + tr * 4] = vhi;
            }
        }
        __syncthreads();
        int rl  = tid >> 3;
        int c16 = (tid & 7) * 16;
#pragma unroll
        for (int q = 0; q < 4; ++q) {
            float4 v = *(const float4*)&tb[rl * 132 + c16 + q * 4];
            uint2 ks;
            ks.x = key16(v.x) | (key16(v.y) << 16);
            ks.y = key16(v.z) | (key16(v.w) << 16);
            *(uint2*)(D + (size_t)(col0 + 32 * p + rl) * N_ + row0 + c16 + q * 4) = ks;
        }
    }
}

// ---------- 64-lane butterfly helpers ----------
__device__ __forceinline__ unsigned long long shflx64(unsigned long long v, int m) {
    unsigned lo = (unsigned)v, hi = (unsigned)(v >> 32);
    lo = (unsigned)__shfl_xor((int)lo, m, 64);
    hi = (unsigned)__shfl_xor((int)hi, m, 64);
    return ((unsigned long long)hi << 32) | lo;
}

// full ascending bitonic sort of one f32 per lane across the wave
__device__ __forceinline__ float bsort64f(float v, int lane) {
#pragma unroll
    for (int k = 2; k <= 64; k <<= 1) {
#pragma unroll
        for (int j = k >> 1; j > 0; j >>= 1) {
            float o = __shfl_xor(v, j, 64);
            bool keepmin = (((lane & j) == 0) == ((lane & k) == 0));
            float mn = fminf(v, o), mx = fmaxf(v, o);
            v = keepmin ? mn : mx;
        }
    }
    return v;
}

// full ascending bitonic sort of one u32 per lane across the wave
__device__ __forceinline__ unsigned bsort64i(unsigned v, int lane) {
#pragma unroll
    for (int k = 2; k <= 64; k <<= 1) {
#pragma unroll
        for (int j = k >> 1; j > 0; j >>= 1) {
            unsigned o = (unsigned)__shfl_xor((int)v, j, 64);
            bool keepmin = (((lane & j) == 0) == ((lane & k) == 0));
            unsigned mn = (v < o) ? v : o;
            unsigned mx = (v < o) ? o : v;
            v = keepmin ? mn : mx;
        }
    }
    return v;
}

// full ascending bitonic sort of one u64 key per lane across the wave
__device__ __forceinline__ unsigned long long bsort64u(unsigned long long v, int lane) {
#pragma unroll
    for (int k = 2; k <= 64; k <<= 1) {
#pragma unroll
        for (int j = k >> 1; j > 0; j >>= 1) {
            unsigned long long o = shflx64(v, j);
            bool keepmin = (((lane & j) == 0) == ((lane & k) == 0));
            bool oless = o < v;
            unsigned long long mn = oless ? o : v;
            unsigned long long mx = oless ? v : o;
            v = keepmin ? mn : mx;
        }
    }
    return v;
}

// ---------- top-20 from u16 key rows: threshold filter -> exact recompute -> bitonic ----------
// key16 is a monotone map of d, so {j : key16[j] <= 20th-smallest key16} is an
// exact superset of the true top-20 (at most 19 keys can be strictly below the
// true 20th's key). tau_grp (20th of 64 lane-mins, min'd over waves) >= that
// 20th key, so the filter is still a superset. Survivors' exact f32 distances
// are recomputed from X (L2-resident) and ranked by (mapf(d), idx) u64 bitonic.
__global__ __launch_bounds__(256) void k_sel(const unsigned short* __restrict__ Dall,
                                             const float* __restrict__ Xall, int C,
                                             const float* __restrict__ xxall,
                                             int* __restrict__ knnIdx, int b0) {
    __shared__ unsigned sidx[SCAP];
    __shared__ unsigned long long skey[SCAP];
    __shared__ float qf[128];
    __shared__ unsigned stau[4];
    __shared__ int scnt;
    int b = b0 + blockIdx.y;
    const unsigned short* Db = Dall + (size_t)blockIdx.y * N_ * N_;
    const float* Xb  = Xall + (size_t)b * N_ * C;
    const float* xxb = xxall + (size_t)b * N_;
    int* idxout = knnIdx + (size_t)b * N_ * KNN_;
    int ql   = blockIdx.x;
    int wv   = threadIdx.x >> 6;
    int lane = threadIdx.x & 63;
    int gbase = wv * 1024 + lane * 16;
    if (threadIdx.x == 0) scnt = 0;
    for (int c = threadIdx.x; c < C; c += 256) qf[c] = Xb[(size_t)ql * C + c];

    const uint4* kp = (const uint4*)(Db + (size_t)ql * N_ + gbase);
    uint4 pa = kp[0], pb = kp[1];
    unsigned kv[16];
    kv[0] = pa.x & 0xffffu;  kv[1] = pa.x >> 16;
    kv[2] = pa.y & 0xffffu;  kv[3] = pa.y >> 16;
    kv[4] = pa.z & 0xffffu;  kv[5] = pa.z >> 16;
    kv[6] = pa.w & 0xffffu;  kv[7] = pa.w >> 16;
    kv[8] = pb.x & 0xffffu;  kv[9] = pb.x >> 16;
    kv[10] = pb.y & 0xffffu; kv[11] = pb.y >> 16;
    kv[12] = pb.z & 0xffffu; kv[13] = pb.z >> 16;
    kv[14] = pb.w & 0xffffu; kv[15] = pb.w >> 16;

    unsigned mn = kv[0];
#pragma unroll
    for (int t = 1; t < 16; ++t) mn = (kv[t] < mn) ? kv[t] : mn;
    mn = bsort64i(mn, lane);
    unsigned tw = (unsigned)__shfl((int)mn, 19, 64);
    if (lane == 0) stau[wv] = tw;
    __syncthreads();
    unsigned tau = stau[0];
    tau = (stau[1] < tau) ? stau[1] : tau;
    tau = (stau[2] < tau) ? stau[2] : tau;
    tau = (stau[3] < tau) ? stau[3] : tau;

#pragma unroll
    for (int t = 0; t < 16; ++t) {
        if (kv[t] <= tau) {
            int p = atomicAdd(&scnt, 1);
            if (p < SCAP) sidx[p] = (unsigned)(gbase + t);
        }
    }
    __syncthreads();
    int S = scnt; if (S > SCAP) S = SCAP;
    float xxq = xxb[ql];
    const float4* xq4 = (const float4*)qf;
    for (int s = threadIdx.x; s < S; s += 256) {
        int j = (int)sidx[s];
        const float4* xj = (const float4*)(Xb + (size_t)j * C);
        float a0 = 0.f, a1 = 0.f, a2 = 0.f, a3 = 0.f;
        for (int c4 = 0; c4 < (C >> 2); ++c4) {
            float4 x = xj[c4]; float4 qv = xq4[c4];
            a0 = fmaf(qv.x, x.x, a0);
            a1 = fmaf(qv.y, x.y, a1);
            a2 = fmaf(qv.z, x.z, a2);
            a3 = fmaf(qv.w, x.w, a3);
        }
        float dot = (a0 + a1) + (a2 + a3);
        float d = xxq + xxb[j] - 2.f * dot;
        skey[s] = ((unsigned long long)mapf(d) << 32) | (unsigned)j;
    }
    __syncthreads();
    if (wv != 0) return;
    unsigned long long key = (lane < S) ? skey[lane] : ~0ull;
    key = bsort64u(key, lane);
    for (int consumed = 64; consumed < S; consumed += 44) {
        if (lane >= 20) {
            int src = consumed + lane - 20;
            key = (src < S) ? skey[src] : ~0ull;
        }
        key = bsort64u(key, lane);
    }
    if (lane < KNN_) idxout[ql * KNN_ + lane] = (int)(unsigned)key;
}

// ---------- layer-1 fused dist+select (C=3), f32 threshold+compaction scheme ----------
__global__ __launch_bounds__(256) void k_selC3(const float* __restrict__ V,
                                               const float* __restrict__ xx,
                                               int* __restrict__ knnIdx) {
    __shared__ unsigned long long sbuf[SCAP];
    __shared__ float stau[4];
    __shared__ int scnt;
    int b    = blockIdx.y;
    const float* Xb  = V + (size_t)b * N_ * 3;
    const float* xxb = xx + (size_t)b * N_;
    int* idxout = knnIdx + (size_t)b * N_ * KNN_;
    int q    = blockIdx.x;
    int wv   = threadIdx.x >> 6;
    int lane = threadIdx.x & 63;
    int gbase = wv * 1024 + lane * 16;
    if (threadIdx.x == 0) scnt = 0;

    float qx = Xb[q * 3], qy = Xb[q * 3 + 1], qz = Xb[q * 3 + 2];
    float xxq = xxb[q];

    float pts[48];
    const float4* src = (const float4*)(Xb + (size_t)gbase * 3);
#pragma unroll
    for (int t = 0; t < 12; ++t) ((float4*)pts)[t] = src[t];

    float dv[16];
#pragma unroll
    for (int t = 0; t < 16; ++t) {
        float dot = qx * pts[3 * t];
        dot = fmaf(qy, pts[3 * t + 1], dot);
        dot = fmaf(qz, pts[3 * t + 2], dot);
        dv[t] = xxq + xxb[gbase + t] - 2.f * dot;
    }

    float mn = dv[0];
#pragma unroll
    for (int t = 1; t < 16; ++t) mn = fminf(mn, dv[t]);
    mn = bsort64f(mn, lane);
    float tw = __shfl(mn, 19, 64);
    if (lane == 0) stau[wv] = tw;
    __syncthreads();
    float tau = fminf(fminf(stau[0], stau[1]), fminf(stau[2], stau[3]));

#pragma unroll
    for (int t = 0; t < 16; ++t) {
        if (dv[t] <= tau) {
            int p = atomicAdd(&scnt, 1);
            if (p < SCAP)
                sbuf[p] = ((unsigned long long)mapf(dv[t]) << 32) | (unsigned)(gbase + t);
        }
    }
    __syncthreads();
    if (wv != 0) return;
    int S = scnt; if (S > SCAP) S = SCAP;
    unsigned long long key = (lane < S) ? sbuf[lane] : ~0ull;
    key = bsort64u(key, lane);
    for (int consumed = 64; consumed < S; consumed += 44) {
        if (lane >= 20) {
            int srci = consumed + lane - 20;
            key = (srci < S) ? sbuf[srci] : ~0ull;
        }
        key = bsort64u(key, lane);
    }
    if (lane < KNN_) idxout[q * KNN_ + lane] = (int)(unsigned)key;
}

// ---------- fused weight prep ----------
__device__ __forceinline__ void prepP_elem(const float* __restrict__ w,
                                           const float* __restrict__ bias,
                                           int C, int O, float* __restrict__ P,
                                           float* __restrict__ b2, int i) {
    int O2 = 2 * O;
    if (i < O2) b2[i] = (i < O) ? 0.f : bias[i - O];
    if (i >= C * O2) return;
    int k = i / O2, col = i % O2;
    float v;
    if (col < O) v = w[(size_t)col * 2 * C + k];
    else { int o = col - O; v = w[(size_t)o * 2 * C + C + k] - w[(size_t)o * 2 * C + k]; }
    P[i] = v;
}
__device__ __forceinline__ void transp_elem(const float* __restrict__ w, int O, int K,
                                            float* __restrict__ wT, int i) {
    if (i >= O * K) return;
    int k = i / O, o = i % O;
    wT[i] = w[(size_t)o * K + k];
}

__global__ void k_prepall(const float* g1w, const float* g1b,
                          const float* g2w, const float* g2b,
                          const float* g3w, const float* g3b,
                          const float* s1w, const float* s1b,
                          const float* s2w, const float* s2b,
                          const float* s3w, const float* s3b,
                          const float* m1w, const float* m2w, const float* m3w,
                          float* P1, float* P2, float* P3, float* P4, float* P5,
                          float* P6, float* P7, float* P8, float* P9,
                          float* bb1, float* bb2, float* bb3,
                          float* bb4, float* bb5, float* bb6) {
    int i = blockIdx.x * 256 + threadIdx.x;
    switch (blockIdx.y) {
        case 0: prepP_elem(g1w, g1b, 3,   64,  P1, bb1, i); break;
        case 1: prepP_elem(g2w, g2b, 64,  128, P2, bb2, i); break;
        case 2: prepP_elem(g3w, g3b, 128, 256, P3, bb3, i); break;
        case 3: prepP_elem(s1w, s1b, 451, 256, P4, bb4, i); break;
        case 4: prepP_elem(s2w, s2b, 256, 128, P5, bb5, i); break;
        case 5: prepP_elem(s3w, s3b, 128, 64,  P6, bb6, i); break;
        case 6: transp_elem(m1w, 512, 448, P7, i); break;
        case 7: transp_elem(m2w, 256, 512, P8, i); break;
        case 8: transp_elem(m3w, 3,   256, P9, i); break;
    }
}

// ---------- tiled f32 GEMM (large M) ----------
__global__ __launch_bounds__(256) void k_gemm(const float* __restrict__ A, int lda,
                                              const float* __restrict__ Bm,
                                              float* __restrict__ Cm, int ldc,
                                              int M, int N, int K,
                                              const float* __restrict__ bias, int leaky) {
    __shared__ float As[16][68];
    __shared__ float Bs[16][68];
    int tid = threadIdx.x;
    int row0 = blockIdx.y * 64, col0 = blockIdx.x * 64;
    int tr = tid >> 4, tc = tid & 15;
    float acc[4][4] = {{0.f}};
    for (int kt = 0; kt < K; kt += 16) {
#pragma unroll
        for (int i = 0; i < 4; ++i) {
            int e = tid + 256 * i;
            int r = e >> 4, kk = e & 15;
            int gr = row0 + r, gk = kt + kk;
            float v = 0.f;
            if (gr < M && gk < K) v = A[(size_t)gr * lda + gk];
            As[kk][r] = v;
        }
#pragma unroll
        for (int i = 0; i < 4; ++i) {
            int e = tid + 256 * i;
            int kk = e >> 6, c = e & 63;
            int gk = kt + kk, gc = col0 + c;
            float v = 0.f;
            if (gk < K && gc < N) v = Bm[(size_t)gk * N + gc];
            Bs[kk][c] = v;
        }
        __syncthreads();
#pragma unroll
        for (int kk = 0; kk < 16; ++kk) {
            float a[4], bv[4];
            *(float4*)&a[0]  = *(const float4*)&As[kk][tr * 4];
            *(float4*)&bv[0] = *(const float4*)&Bs[kk][tc * 4];
#pragma unroll
            for (int i = 0; i < 4; ++i)
#pragma unroll
                for (int j = 0; j < 4; ++j) acc[i][j] += a[i] * bv[j];
        }
        __syncthreads();
    }
#pragma unroll
    for (int i = 0; i < 4; ++i) {
        int r = row0 + tr * 4 + i;
        if (r >= M) continue;
#pragma unroll
        for (int j = 0; j < 4; ++j) {
            int c = col0 + tc * 4 + j;
            if (c >= N) continue;
            float v = acc[i][j];
            if (bias) v += bias[c];
            if (leaky) v = v >= 0.f ? v : SLOPE * v;
            Cm[(size_t)r * ldc + c] = v;
        }
    }
}

// ---------- small-M GEMM ----------
__global__ __launch_bounds__(256) void k_sgemm(const float* __restrict__ A, int lda,
                                               const float* __restrict__ Bm,
                                               float* __restrict__ Cm, int ldc,
                                               int N, int K,
                                               const float* __restrict__ bias, int leaky) {
    extern __shared__ float Arow[];
    int r   = blockIdx.x;
    int c0  = blockIdx.y * 256;
    int tid = threadIdx.x;
    for (int k = tid; k < K; k += 256) Arow[k] = A[(size_t)r * lda + k];
    __syncthreads();
    int c = c0 + tid;
    if (c >= N) return;
    float acc = bias ? bias[c] : 0.f;
    for (int k = 0; k < K; ++k) acc += Arow[k] * Bm[(size_t)k * N + c];
    if (leaky) acc = acc >= 0.f ? acc : SLOPE * acc;
    Cm[(size_t)r * ldc + c] = acc;
}

// ---------- gather-max epilogue (+ optional fused row-norm) ----------
__global__ void k_gathermax(const float* __restrict__ Y, int O, int R,
                            const int* __restrict__ idx, int kc,
                            float* __restrict__ out, int ldo, int ooff,
                            float* __restrict__ xxout) {
    extern __shared__ int sidx[];
    __shared__ float red[256];
    int br = blockIdx.x;
    int b  = br / R;
    int o  = threadIdx.x;
    if (o < kc) sidx[o] = idx[(size_t)br * kc + o];
    __syncthreads();
    int O2 = 2 * O;
    float z = Y[(size_t)br * O2 + O + o];
    float best = -FLT_MAX;
    for (int k = 0; k < kc; ++k) {
        int m = sidx[k];
        best = fmaxf(best, Y[(size_t)(b * R + m) * O2 + o]);
    }
    float r = z + best;
    r = r >= 0.f ? r : SLOPE * r;
    out[(size_t)br * ldo + ooff + o] = r;
    if (xxout) {
        red[o] = r * r;
        __syncthreads();
        for (int s = blockDim.x >> 1; s > 0; s >>= 1) {
            if (o < s) red[o] += red[o + s];
            __syncthreads();
        }
        if (o == 0) xxout[br] = red[0];
    }
}

// ---------- channel map ----------
__device__ __forceinline__ void chan_map(int b, int c,
                                         const float* Vf, const float* l1,
                                         const float* l2, const float* l3,
                                         const float*& p, int& st) {
    if (c < 3)        { st = 3;   p = Vf + (size_t)b * N_ * 3   + c; }
    else if (c < 67)  { st = 64;  p = l1 + (size_t)b * N_ * 64  + (c - 3); }
    else if (c < 195) { st = 128; p = l2 + (size_t)b * N_ * 128 + (c - 67); }
    else              { st = 256; p = l3 + (size_t)b * N_ * 256 + (c - 195); }
}

// ---------- pooling phase 1 ----------
__global__ __launch_bounds__(256) void k_pool2(const float* __restrict__ Vf,
                                               const float* __restrict__ l1,
                                               const float* __restrict__ l2,
                                               const float* __restrict__ l3,
                                               const float* __restrict__ W,
                                               float* __restrict__ ppool,
                                               float* __restrict__ psw) {
    __shared__ float Wl[SLABN][J_];
    int blk  = blockIdx.x;
    int b    = blk / NSLAB, slab = blk % NSLAB;
    int n0   = slab * SLABN;
    int tid  = threadIdx.x;

    for (int e = tid; e < J_ * SLABN; e += 256) {
        int j = e / SLABN, n = e % SLABN;
        Wl[n][j] = W[((size_t)b * J_ + j) * N_ + n0 + n];
    }
    __syncthreads();

    if (tid < J_) {
        float s = 0.f;
        for (int n = 0; n < SLABN; ++n) s += Wl[n][tid];
        psw[(size_t)blk * J_ + tid] = s;
    }

    int c0 = tid, c1 = tid + 256;
    const float *p0, *p1 = nullptr; int s0, s1 = 0;
    chan_map(b, c0, Vf, l1, l2, l3, p0, s0);
    bool has1 = (c1 < 451);
    if (has1) chan_map(b, c1, Vf, l1, l2, l3, p1, s1);

    float acc0[J_], acc1[J_];
#pragma unroll
    for (int j = 0; j < J_; ++j) { acc0[j] = 0.f; acc1[j] = 0.f; }

    for (int n = 0; n < SLABN; ++n) {
        float v0 = p0[(size_t)(n0 + n) * s0];
        float v1 = has1 ? p1[(size_t)(n0 + n) * s1] : 0.f;
        const float* wn = &Wl[n][0];
#pragma unroll
        for (int q = 0; q < J_ / 4; ++q) {
            float4 w4 = *(const float4*)(wn + 4 * q);
            acc0[4*q+0] += w4.x * v0;  acc1[4*q+0] += w4.x * v1;
            acc0[4*q+1] += w4.y * v0;  acc1[4*q+1] += w4.y * v1;
            acc0[4*q+2] += w4.z * v0;  acc1[4*q+2] += w4.z * v1;
            acc0[4*q+3] += w4.w * v0;  acc1[4*q+3] += w4.w * v1;
        }
    }
    float* pp = ppool + (size_t)blk * J_ * 451;
#pragma unroll
    for (int j = 0; j < J_; ++j) {
        pp[(size_t)j * 451 + c0] = acc0[j];
        if (has1) pp[(size_t)j * 451 + c1] = acc1[j];
    }
}

// ---------- pooling phase 2 ----------
__global__ __launch_bounds__(256) void k_poolred(const float* __restrict__ ppool,
                                                 const float* __restrict__ psw,
                                                 float* __restrict__ pooled) {
    int bj = blockIdx.x;
    int b  = bj / J_, j = bj % J_;
    int tid = threadIdx.x;

    float sw = 0.f;
    for (int sl = 0; sl < NSLAB; ++sl) sw += psw[(size_t)(b * NSLAB + sl) * J_ + j];
    float inv = 1.f / (sw + 1e-5f);

    for (int c = tid; c < 451; c += 256) {
        float s = 0.f;
        for (int sl = 0; sl < NSLAB; ++sl)
            s += ppool[((size_t)(b * NSLAB + sl) * J_ + j) * 451 + c];
        pooled[(size_t)bj * 451 + c] = s * inv;
    }
}

extern "C" void kernel_launch(void* const* d_in, const int* in_sizes, int n_in,
                              void* d_out, int out_size, void* d_ws, size_t ws_size,
                              hipStream_t stream) {
    const float* V  = (const float*)d_in[0];
    const float* W  = (const float*)d_in[1];
    const int* ringIdx = (const int*)d_in[2];
    const float* g1w = (const float*)d_in[3];
    const float* g1b = (const float*)d_in[4];
    const float* g2w = (const float*)d_in[5];
    const float* g2b = (const float*)d_in[6];
    const float* g3w = (const float*)d_in[7];
    const float* g3b = (const float*)d_in[8];
    const float* s1w = (const float*)d_in[9];
    const float* s1b = (const float*)d_in[10];
    const float* s2w = (const float*)d_in[11];
    const float* s2b = (const float*)d_in[12];
    const float* s3w = (const float*)d_in[13];
    const float* s3b = (const float*)d_in[14];
    const float* m1w = (const float*)d_in[15];
    const float* m1b = (const float*)d_in[16];
    const float* m2w = (const float*)d_in[17];
    const float* m2b = (const float*)d_in[18];
    const float* m3w = (const float*)d_in[19];
    const float* m3b = (const float*)d_in[20];
    (void)n_in; (void)in_sizes; (void)out_size;

    const int szP1 = 3 * 128,    szP2 = 64 * 256,  szP3 = 128 * 512;
    const int szP4 = 451 * 512,  szP5 = 256 * 256, szP6 = 128 * 128;
    const int szP7 = 448 * 512,  szP8 = 512 * 256, szP9 = 256 * 3;

    // D region (floats): nd key-buffers (u16, N*N/2 floats each), must also
    // cover Y (M*512 f32) and the pooling scratch that alias it.
    auto dreg_floats = [&](int nd) -> size_t {
        size_t a = (size_t)nd * ((size_t)N_ * N_ / 2);
        size_t ymax = (size_t)B_ * N_ * 512;                       // 8.39M floats
        size_t pool = (size_t)B_ * NSLAB * J_ * 451 + (size_t)B_ * NSLAB * J_;
        size_t r = a;
        if (ymax > r) r = ymax;
        if (pool > r) r = pool;
        return r;
    };
    auto layout_bytes = [&](int nd) -> size_t {
        size_t f = 0;
        f += (size_t)B_ * N_ * 64 + (size_t)B_ * N_ * 128 + (size_t)B_ * N_ * 256;
        f += (size_t)B_ * N_;                         // xx
        f += dreg_floats(nd);                         // D/Y/pool region
        f += (size_t)B_ * N_ * KNN_;                  // knnIdx (ints)
        f += (size_t)B_ * J_ * 451 + (size_t)B_ * J_ * 448;
        f += (size_t)B_ * J_ * 512 + (size_t)B_ * J_ * 256;
        f += (size_t)(szP1 + szP2 + szP3 + szP4 + szP5 + szP6 + szP7 + szP8 + szP9);
        f += 128 + 256 + 512 + 512 + 256 + 128;
        return f * 4;
    };
    // nb = batches per dist/sel group (deterministic in ws_size -> graph-safe)
    int nb = 1;
    if (ws_size >= layout_bytes(4)) nb = 4;
    else if (ws_size >= layout_bytes(2)) nb = 2;

    // ---- workspace layout (floats) ----
    float* ws = (float*)d_ws;
    size_t off = 0;
    float* l1 = ws + off; off += (size_t)B_ * N_ * 64;
    float* l2 = ws + off; off += (size_t)B_ * N_ * 128;
    float* l3 = ws + off; off += (size_t)B_ * N_ * 256;
    float* xx = ws + off; off += (size_t)B_ * N_;
    float* D  = ws + off; off += dreg_floats(nb);        // keys / Y / pool region
    unsigned short* Dk = (unsigned short*)D;
    float* Y  = D;
    float* ppool = D;
    float* psw   = D + (size_t)B_ * NSLAB * J_ * 451;
    int* knnIdx = (int*)(ws + off); off += (size_t)B_ * N_ * KNN_;
    float* pooled = ws + off; off += (size_t)B_ * J_ * 451;
    float* joints = ws + off; off += (size_t)B_ * J_ * 448;
    float* h1 = ws + off; off += (size_t)B_ * J_ * 512;
    float* h2 = ws + off; off += (size_t)B_ * J_ * 256;
    float* P1 = ws + off; off += szP1;
    float* P2 = ws + off; off += szP2;
    float* P3 = ws + off; off += szP3;
    float* P4 = ws + off; off += szP4;
    float* P5 = ws + off; off += szP5;
    float* P6 = ws + off; off += szP6;
    float* P7 = ws + off; off += szP7;
    float* P8 = ws + off; off += szP8;
    float* P9 = ws + off; off += szP9;
    float* bb1 = ws + off; off += 128;
    float* bb2 = ws + off; off += 256;
    float* bb3 = ws + off; off += 512;
    float* bb4 = ws + off; off += 512;
    float* bb5 = ws + off; off += 256;
    float* bb6 = ws + off; off += 128;

    const int M = B_ * N_;   // 16384
    const int MJ = B_ * J_;  // 96
    const int NUTRI = NTILE * (NTILE + 1) / 2;   // 528 upper-tri tiles

    // ---- all weight prep in one launch ----
    k_prepall<<<dim3((szP4 + 255) / 256, 9), 256, 0, stream>>>(
        g1w, g1b, g2w, g2b, g3w, g3b, s1w, s1b, s2w, s2b, s3w, s3b,
        m1w, m2w, m3w, P1, P2, P3, P4, P5, P6, P7, P8, P9,
        bb1, bb2, bb3, bb4, bb5, bb6);

    // ======== geoNet layer 1: C=3 -> O=64 (fused dist+select) ========
    k_norm<<<(M + 255) / 256, 256, 0, stream>>>(V, xx, 3);
    k_selC3<<<dim3(N_, B_), 256, 0, stream>>>(V, xx, knnIdx);
    k_gemm<<<dim3(2, M / 64), 256, 0, stream>>>(V, 3, P1, Y, 128, M, 128, 3, bb1, 0);
    k_gathermax<<<M, 64, KNN_ * sizeof(int), stream>>>(Y, 64, N_, knnIdx, KNN_, l1, 64, 0, xx);

    // ======== layer 2: C=64 -> O=128 ========
    for (int g = 0; g < B_; g += nb) {
        k_dist<<<dim3(NUTRI, nb), 256, 0, stream>>>(l1, 64, xx, Dk, g);
        k_sel<<<dim3(N_, nb), 256, 0, stream>>>(Dk, l1, 64, xx, knnIdx, g);
    }
    k_gemm<<<dim3(4, M / 64), 256, 0, stream>>>(l1, 64, P2, Y, 256, M, 256, 64, bb2, 0);
    k_gathermax<<<M, 128, KNN_ * sizeof(int), stream>>>(Y, 128, N_, knnIdx, KNN_, l2, 128, 0, xx);

    // ======== layer 3: C=128 -> O=256 ========
    for (int g = 0; g < B_; g += nb) {
        k_dist<<<dim3(NUTRI, nb), 256, 0, stream>>>(l2, 128, xx, Dk, g);
        k_sel<<<dim3(N_, nb), 256, 0, stream>>>(Dk, l2, 128, xx, knnIdx, g);
    }
    k_gemm<<<dim3(8, M / 64), 256, 0, stream>>>(l2, 128, P3, Y, 512, M, 512, 128, bb3, 0);
    k_gathermax<<<M, 256, KNN_ * sizeof(int), stream>>>(Y, 256, N_, knnIdx, KNN_, l3, 256, 0, nullptr);

    // ======== pooling onto joints ========
    k_pool2<<<B_ * NSLAB, 256, 0, stream>>>(V, l1, l2, l3, W, ppool, psw);
    k_poolred<<<MJ, 256, 0, stream>>>(ppool, psw, pooled);

    // ======== skeleton convs ========
    k_sgemm<<<dim3(MJ, 2), 256, 451 * sizeof(float), stream>>>(pooled, 451, P4, Y, 512, 512, 451, bb4, 0);
    k_gathermax<<<MJ, 256, KR_ * sizeof(int), stream>>>(Y, 256, J_, ringIdx, KR_, joints, 448, 0, nullptr);

    k_sgemm<<<dim3(MJ, 1), 256, 256 * sizeof(float), stream>>>(joints, 448, P5, Y, 256, 256, 256, bb5, 0);
    k_gathermax<<<MJ, 128, KR_ * sizeof(int), stream>>>(Y, 128, J_, ringIdx, KR_, joints, 448, 256, nullptr);

    k_sgemm<<<dim3(MJ, 1), 256, 128 * sizeof(float), stream>>>(joints + 256, 448, P6, Y, 128, 128, 128, bb6, 0);
    k_gathermax<<<MJ, 64, KR_ * sizeof(int), stream>>>(Y, 64, J_, ringIdx, KR_, joints, 448, 384, nullptr);

    // ======== joint MLP ========
    k_sgemm<<<dim3(MJ, 2), 256, 448 * sizeof(float), stream>>>(joints, 448, P7, h1, 512, 512, 448, m1b, 1);
    k_sgemm<<<dim3(MJ, 1), 256, 512 * sizeof(float), stream>>>(h1, 512, P8, h2, 256, 256, 512, m2b, 1);
    k_sgemm<<<dim3(MJ, 1), 256, 256 * sizeof(float), stream>>>(h2, 256, P9, (float*)d_out, 3, 3, 256, m3b, 0);
}

// Round 3
// 946.469 us; speedup vs baseline: 1.3722x; 1.0522x over previous
//
#include <hip/hip_runtime.h>
#include <hip/hip_bf16.h>
#include <float.h>

// Problem constants (from reference setup_inputs)
#define B_   4
#define N_   4096
#define J_   24
#define KR_  4
#define KNN_ 20
#define SLOPE 0.2f
#define SLABN 64             // points per pooling slab
#define NSLAB (N_ / SLABN)   // 64
#define NTILE 32             // 128-wide tiles per dim
#define SCAP 768             // survivor buffer cap
#define KSLACK 8u            // u16-key slack covering split-bf16 error

typedef __attribute__((ext_vector_type(8))) short bf16x8;
typedef __attribute__((ext_vector_type(4))) float f32x4;

// ---------- per-point squared norm ----------
__global__ void k_norm(const float* __restrict__ h, float* __restrict__ xx, int C) {
    int i = blockIdx.x * blockDim.x + threadIdx.x;
    if (i >= B_ * N_) return;
    const float* hp = h + (size_t)i * C;
    float s = 0.f;
    for (int c = 0; c < C; ++c) { float v = hp[c]; s += v * v; }
    xx[i] = s;
}

// ---------- monotone key maps ----------
__device__ __forceinline__ unsigned mapf(float f) {
    unsigned u = __float_as_uint(f);
    return (u & 0x80000000u) ? ~u : (u | 0x80000000u);
}
// top-16 bits of mapf: monotone f32 -> u16 (truncation preserves order)
__device__ __forceinline__ unsigned key16(float f) {
    return mapf(f) >> 16;
}

// ---------- split f32 -> bf16 hi + bf16 lo (both truncated; x = hi + lo + r, |r|<=2^-16|x|) ----------
__global__ void k_split(const float* __restrict__ h, unsigned short* __restrict__ hi,
                        unsigned short* __restrict__ lo, int total4) {
    int i = blockIdx.x * 256 + threadIdx.x;
    if (i >= total4) return;
    float4 v = ((const float4*)h)[i];
    ushort4 h4, l4;
    {
        unsigned u = __float_as_uint(v.x); h4.x = (unsigned short)(u >> 16);
        float r = v.x - __uint_as_float(u & 0xffff0000u); l4.x = (unsigned short)(__float_as_uint(r) >> 16);
    }
    {
        unsigned u = __float_as_uint(v.y); h4.y = (unsigned short)(u >> 16);
        float r = v.y - __uint_as_float(u & 0xffff0000u); l4.y = (unsigned short)(__float_as_uint(r) >> 16);
    }
    {
        unsigned u = __float_as_uint(v.z); h4.z = (unsigned short)(u >> 16);
        float r = v.z - __uint_as_float(u & 0xffff0000u); l4.z = (unsigned short)(__float_as_uint(r) >> 16);
    }
    {
        unsigned u = __float_as_uint(v.w); h4.w = (unsigned short)(u >> 16);
        float r = v.w - __uint_as_float(u & 0xffff0000u); l4.w = (unsigned short)(__float_as_uint(r) >> 16);
    }
    ((ushort4*)hi)[i] = h4;
    ((ushort4*)lo)[i] = l4;
}

// ---------- MFMA distance GEMM (split-bf16, 3-pass) -> u16 keys ----------
// Upper-tri 128x128 tiles; 4 waves, each computing a 64x64 quadrant via
// 4x4 frags of mfma_f32_16x16x32_bf16. A/B frags load directly from L2-resident
// row-major bf16 [pt][k] arrays: pt = lane&15 (+frag offset), k = ks + 8*(lane>>4)+e.
__global__ __launch_bounds__(256) void k_dist(const unsigned short* __restrict__ Hi,
                                              const unsigned short* __restrict__ Lo,
                                              int C,
                                              const float* __restrict__ xxall,
                                              unsigned short* __restrict__ Dall, int b0) {
    __shared__ unsigned short tile[128][136];   // +8 pad: 272B rows, 16B-aligned
    int b = b0 + blockIdx.y;
    const unsigned short* XH = Hi + (size_t)b * N_ * C;
    const unsigned short* XL = Lo + (size_t)b * N_ * C;
    const float* xxb = xxall + (size_t)b * N_;
    unsigned short* D = Dall + (size_t)blockIdx.y * N_ * N_;

    int t = blockIdx.x;                      // linear upper-tri tile id
    int ti = 0;
    while (t >= NTILE - ti) { t -= NTILE - ti; ++ti; }
    int tj = ti + t;
    int row0 = ti * 128, col0 = tj * 128;
    int tid  = threadIdx.x;
    int wv   = tid >> 6, lane = tid & 63;
    int wr   = wv >> 1,  wc   = wv & 1;
    int rbase = row0 + wr * 64;
    int cbase = col0 + wc * 64;
    int lp    = lane & 15;        // point within frag
    int kgrp  = lane >> 4;        // k-group

    f32x4 acc[4][4];
#pragma unroll
    for (int i = 0; i < 4; ++i)
#pragma unroll
        for (int j = 0; j < 4; ++j) acc[i][j] = (f32x4){0.f, 0.f, 0.f, 0.f};

    for (int ks = 0; ks < C; ks += 32) {
        int kb = ks + kgrp * 8;
        bf16x8 ah[4], al[4];
#pragma unroll
        for (int fi = 0; fi < 4; ++fi) {
            size_t ro = (size_t)(rbase + fi * 16 + lp) * C + kb;
            ah[fi] = *(const bf16x8*)(XH + ro);
            al[fi] = *(const bf16x8*)(XL + ro);
        }
#pragma unroll
        for (int fj = 0; fj < 4; ++fj) {
            size_t co = (size_t)(cbase + fj * 16 + lp) * C + kb;
            bf16x8 bh = *(const bf16x8*)(XH + co);
            bf16x8 bl = *(const bf16x8*)(XL + co);
#pragma unroll
            for (int fi = 0; fi < 4; ++fi) {
                acc[fi][fj] = __builtin_amdgcn_mfma_f32_16x16x32_bf16(ah[fi], bh, acc[fi][fj], 0, 0, 0);
                acc[fi][fj] = __builtin_amdgcn_mfma_f32_16x16x32_bf16(ah[fi], bl, acc[fi][fj], 0, 0, 0);
                acc[fi][fj] = __builtin_amdgcn_mfma_f32_16x16x32_bf16(al[fi], bh, acc[fi][fj], 0, 0, 0);
            }
        }
    }

    // epilogue: d = xxr + xxc - 2*dot -> u16 key into LDS tile
    float xxrv = xxb[rbase + lane];
    float xxcv = xxb[cbase + lane];
    int rsub = (lane >> 4) * 4;
#pragma unroll
    for (int fi = 0; fi < 4; ++fi) {
#pragma unroll
        for (int fj = 0; fj < 4; ++fj) {
            float xc = __shfl(xxcv, fj * 16 + lp, 64);
#pragma unroll
            for (int r = 0; r < 4; ++r) {
                float xr = __shfl(xxrv, fi * 16 + rsub + r, 64);
                float d = xr + xc - 2.f * acc[fi][fj][r];
                tile[wr * 64 + fi * 16 + rsub + r][wc * 64 + fj * 16 + lp] =
                    (unsigned short)key16(d);
            }
        }
    }
    __syncthreads();

    // normal store: coalesced 128B segments per thread
    {
        int row = tid >> 1, seg = (tid & 1) * 64;
        const uint4* src = (const uint4*)&tile[row][seg];
        uint4* dst = (uint4*)(D + (size_t)(row0 + row) * N_ + col0 + seg);
#pragma unroll
        for (int q = 0; q < 8; ++q) dst[q] = src[q];
    }
    if (ti == tj) return;
    // mirror store: column gather from LDS, contiguous 128B global segments
    {
        int c = tid >> 1, rseg = (tid & 1) * 64;
        unsigned short* dst = D + (size_t)(col0 + c) * N_ + row0 + rseg;
#pragma unroll
        for (int q8 = 0; q8 < 8; ++q8) {
            unsigned short s[8];
#pragma unroll
            for (int q = 0; q < 8; ++q) s[q] = tile[rseg + q8 * 8 + q][c];
            *(uint4*)(dst + q8 * 8) = *(const uint4*)s;
        }
    }
}

// ---------- 64-lane butterfly helpers ----------
__device__ __forceinline__ unsigned long long shflx64(unsigned long long v, int m) {
    unsigned lo = (unsigned)v, hi = (unsigned)(v >> 32);
    lo = (unsigned)__shfl_xor((int)lo, m, 64);
    hi = (unsigned)__shfl_xor((int)hi, m, 64);
    return ((unsigned long long)hi << 32) | lo;
}

// full ascending bitonic sort of one f32 per lane across the wave
__device__ __forceinline__ float bsort64f(float v, int lane) {
#pragma unroll
    for (int k = 2; k <= 64; k <<= 1) {
#pragma unroll
        for (int j = k >> 1; j > 0; j >>= 1) {
            float o = __shfl_xor(v, j, 64);
            bool keepmin = (((lane & j) == 0) == ((lane & k) == 0));
            float mn = fminf(v, o), mx = fmaxf(v, o);
            v = keepmin ? mn : mx;
        }
    }
    return v;
}

// full ascending bitonic sort of one u32 per lane across the wave
__device__ __forceinline__ unsigned bsort64i(unsigned v, int lane) {
#pragma unroll
    for (int k = 2; k <= 64; k <<= 1) {
#pragma unroll
        for (int j = k >> 1; j > 0; j >>= 1) {
            unsigned o = (unsigned)__shfl_xor((int)v, j, 64);
            bool keepmin = (((lane & j) == 0) == ((lane & k) == 0));
            unsigned mn = (v < o) ? v : o;
            unsigned mx = (v < o) ? o : v;
            v = keepmin ? mn : mx;
        }
    }
    return v;
}

// full ascending bitonic sort of one u64 key per lane across the wave
__device__ __forceinline__ unsigned long long bsort64u(unsigned long long v, int lane) {
#pragma unroll
    for (int k = 2; k <= 64; k <<= 1) {
#pragma unroll
        for (int j = k >> 1; j > 0; j >>= 1) {
            unsigned long long o = shflx64(v, j);
            bool keepmin = (((lane & j) == 0) == ((lane & k) == 0));
            bool oless = o < v;
            unsigned long long mn = oless ? o : v;
            unsigned long long mx = oless ? v : o;
            v = keepmin ? mn : mx;
        }
    }
    return v;
}

// ---------- top-20 from u16 key rows: slacked threshold -> exact recompute -> bitonic ----------
// Keys are monotone maps of the split-bf16 approx distance (error delta). With
// tau = (20th of lane-mins, min over waves) and filter key <= tau + KSLACK,
// the survivor set is a superset of the exact top-20 whenever KSLACK covers
// 2*delta in key space (margin here ~1e4x). Survivors' exact f32 distances are
// recomputed from X and ranked by (mapf(d), idx) u64 bitonic -> exact result.
__global__ __launch_bounds__(256) void k_sel(const unsigned short* __restrict__ Dall,
                                             const float* __restrict__ Xall, int C,
                                             const float* __restrict__ xxall,
                                             int* __restrict__ knnIdx, int b0) {
    __shared__ unsigned sidx[SCAP];
    __shared__ unsigned long long skey[SCAP];
    __shared__ float qf[128];
    __shared__ unsigned stau[4];
    __shared__ int scnt;
    int b = b0 + blockIdx.y;
    const unsigned short* Db = Dall + (size_t)blockIdx.y * N_ * N_;
    const float* Xb  = Xall + (size_t)b * N_ * C;
    const float* xxb = xxall + (size_t)b * N_;
    int* idxout = knnIdx + (size_t)b * N_ * KNN_;
    int ql   = blockIdx.x;
    int wv   = threadIdx.x >> 6;
    int lane = threadIdx.x & 63;
    int gbase = wv * 1024 + lane * 16;
    if (threadIdx.x == 0) scnt = 0;
    for (int c = threadIdx.x; c < C; c += 256) qf[c] = Xb[(size_t)ql * C + c];

    const uint4* kp = (const uint4*)(Db + (size_t)ql * N_ + gbase);
    uint4 pa = kp[0], pb = kp[1];
    unsigned kv[16];
    kv[0] = pa.x & 0xffffu;  kv[1] = pa.x >> 16;
    kv[2] = pa.y & 0xffffu;  kv[3] = pa.y >> 16;
    kv[4] = pa.z & 0xffffu;  kv[5] = pa.z >> 16;
    kv[6] = pa.w & 0xffffu;  kv[7] = pa.w >> 16;
    kv[8] = pb.x & 0xffffu;  kv[9] = pb.x >> 16;
    kv[10] = pb.y & 0xffffu; kv[11] = pb.y >> 16;
    kv[12] = pb.z & 0xffffu; kv[13] = pb.z >> 16;
    kv[14] = pb.w & 0xffffu; kv[15] = pb.w >> 16;

    unsigned mn = kv[0];
#pragma unroll
    for (int t = 1; t < 16; ++t) mn = (kv[t] < mn) ? kv[t] : mn;
    mn = bsort64i(mn, lane);
    unsigned tw = (unsigned)__shfl((int)mn, 19, 64);
    if (lane == 0) stau[wv] = tw;
    __syncthreads();
    unsigned tau = stau[0];
    tau = (stau[1] < tau) ? stau[1] : tau;
    tau = (stau[2] < tau) ? stau[2] : tau;
    tau = (stau[3] < tau) ? stau[3] : tau;
    tau += KSLACK;
    if (tau > 0xffffu) tau = 0xffffu;

#pragma unroll
    for (int t = 0; t < 16; ++t) {
        if (kv[t] <= tau) {
            int p = atomicAdd(&scnt, 1);
            if (p < SCAP) sidx[p] = (unsigned)(gbase + t);
        }
    }
    __syncthreads();
    int S = scnt; if (S > SCAP) S = SCAP;
    float xxq = xxb[ql];
    const float4* xq4 = (const float4*)qf;
    for (int s = threadIdx.x; s < S; s += 256) {
        int j = (int)sidx[s];
        const float4* xj = (const float4*)(Xb + (size_t)j * C);
        float a0 = 0.f, a1 = 0.f, a2 = 0.f, a3 = 0.f;
        for (int c4 = 0; c4 < (C >> 2); ++c4) {
            float4 x = xj[c4]; float4 qv = xq4[c4];
            a0 = fmaf(qv.x, x.x, a0);
            a1 = fmaf(qv.y, x.y, a1);
            a2 = fmaf(qv.z, x.z, a2);
            a3 = fmaf(qv.w, x.w, a3);
        }
        float dot = (a0 + a1) + (a2 + a3);
        float d = xxq + xxb[j] - 2.f * dot;
        skey[s] = ((unsigned long long)mapf(d) << 32) | (unsigned)j;
    }
    __syncthreads();
    if (wv != 0) return;
    unsigned long long key = (lane < S) ? skey[lane] : ~0ull;
    key = bsort64u(key, lane);
    for (int consumed = 64; consumed < S; consumed += 44) {
        if (lane >= 20) {
            int src = consumed + lane - 20;
            key = (src < S) ? skey[src] : ~0ull;
        }
        key = bsort64u(key, lane);
    }
    if (lane < KNN_) idxout[ql * KNN_ + lane] = (int)(unsigned)key;
}

// ---------- layer-1 fused dist+select (C=3), exact f32 threshold+compaction ----------
__global__ __launch_bounds__(256) void k_selC3(const float* __restrict__ V,
                                               const float* __restrict__ xx,
                                               int* __restrict__ knnIdx) {
    __shared__ unsigned long long sbuf[SCAP];
    __shared__ float stau[4];
    __shared__ int scnt;
    int b    = blockIdx.y;
    const float* Xb  = V + (size_t)b * N_ * 3;
    const float* xxb = xx + (size_t)b * N_;
    int* idxout = knnIdx + (size_t)b * N_ * KNN_;
    int q    = blockIdx.x;
    int wv   = threadIdx.x >> 6;
    int lane = threadIdx.x & 63;
    int gbase = wv * 1024 + lane * 16;
    if (threadIdx.x == 0) scnt = 0;

    float qx = Xb[q * 3], qy = Xb[q * 3 + 1], qz = Xb[q * 3 + 2];
    float xxq = xxb[q];

    float pts[48];
    const float4* src = (const float4*)(Xb + (size_t)gbase * 3);
#pragma unroll
    for (int t = 0; t < 12; ++t) ((float4*)pts)[t] = src[t];

    float dv[16];
#pragma unroll
    for (int t = 0; t < 16; ++t) {
        float dot = qx * pts[3 * t];
        dot = fmaf(qy, pts[3 * t + 1], dot);
        dot = fmaf(qz, pts[3 * t + 2], dot);
        dv[t] = xxq + xxb[gbase + t] - 2.f * dot;
    }

    float mn = dv[0];
#pragma unroll
    for (int t = 1; t < 16; ++t) mn = fminf(mn, dv[t]);
    mn = bsort64f(mn, lane);
    float tw = __shfl(mn, 19, 64);
    if (lane == 0) stau[wv] = tw;
    __syncthreads();
    float tau = fminf(fminf(stau[0], stau[1]), fminf(stau[2], stau[3]));

#pragma unroll
    for (int t = 0; t < 16; ++t) {
        if (dv[t] <= tau) {
            int p = atomicAdd(&scnt, 1);
            if (p < SCAP)
                sbuf[p] = ((unsigned long long)mapf(dv[t]) << 32) | (unsigned)(gbase + t);
        }
    }
    __syncthreads();
    if (wv != 0) return;
    int S = scnt; if (S > SCAP) S = SCAP;
    unsigned long long key = (lane < S) ? sbuf[lane] : ~0ull;
    key = bsort64u(key, lane);
    for (int consumed = 64; consumed < S; consumed += 44) {
        if (lane >= 20) {
            int srci = consumed + lane - 20;
            key = (srci < S) ? sbuf[srci] : ~0ull;
        }
        key = bsort64u(key, lane);
    }
    if (lane < KNN_) idxout[q * KNN_ + lane] = (int)(unsigned)key;
}

// ---------- fused weight prep ----------
__device__ __forceinline__ void prepP_elem(const float* __restrict__ w,
                                           const float* __restrict__ bias,
                                           int C, int O, float* __restrict__ P,
                                           float* __restrict__ b2, int i) {
    int O2 = 2 * O;
    if (i < O2) b2[i] = (i < O) ? 0.f : bias[i - O];
    if (i >= C * O2) return;
    int k = i / O2, col = i % O2;
    float v;
    if (col < O) v = w[(size_t)col * 2 * C + k];
    else { int o = col - O; v = w[(size_t)o * 2 * C + C + k] - w[(size_t)o * 2 * C + k]; }
    P[i] = v;
}
__device__ __forceinline__ void transp_elem(const float* __restrict__ w, int O, int K,
                                            float* __restrict__ wT, int i) {
    if (i >= O * K) return;
    int k = i / O, o = i % O;
    wT[i] = w[(size_t)o * K + k];
}

__global__ void k_prepall(const float* g1w, const float* g1b,
                          const float* g2w, const float* g2b,
                          const float* g3w, const float* g3b,
                          const float* s1w, const float* s1b,
                          const float* s2w, const float* s2b,
                          const float* s3w, const float* s3b,
                          const float* m1w, const float* m2w, const float* m3w,
                          float* P1, float* P2, float* P3, float* P4, float* P5,
                          float* P6, float* P7, float* P8, float* P9,
                          float* bb1, float* bb2, float* bb3,
                          float* bb4, float* bb5, float* bb6) {
    int i = blockIdx.x * 256 + threadIdx.x;
    switch (blockIdx.y) {
        case 0: prepP_elem(g1w, g1b, 3,   64,  P1, bb1, i); break;
        case 1: prepP_elem(g2w, g2b, 64,  128, P2, bb2, i); break;
        case 2: prepP_elem(g3w, g3b, 128, 256, P3, bb3, i); break;
        case 3: prepP_elem(s1w, s1b, 451, 256, P4, bb4, i); break;
        case 4: prepP_elem(s2w, s2b, 256, 128, P5, bb5, i); break;
        case 5: prepP_elem(s3w, s3b, 128, 64,  P6, bb6, i); break;
        case 6: transp_elem(m1w, 512, 448, P7, i); break;
        case 7: transp_elem(m2w, 256, 512, P8, i); break;
        case 8: transp_elem(m3w, 3,   256, P9, i); break;
    }
}

// ---------- tiled f32 GEMM (large M) ----------
__global__ __launch_bounds__(256) void k_gemm(const float* __restrict__ A, int lda,
                                              const float* __restrict__ Bm,
                                              float* __restrict__ Cm, int ldc,
                                              int M, int N, int K,
                                              const float* __restrict__ bias, int leaky) {
    __shared__ float As[16][68];
    __shared__ float Bs[16][68];
    int tid = threadIdx.x;
    int row0 = blockIdx.y * 64, col0 = blockIdx.x * 64;
    int tr = tid >> 4, tc = tid & 15;
    float acc[4][4] = {{0.f}};
    for (int kt = 0; kt < K; kt += 16) {
#pragma unroll
        for (int i = 0; i < 4; ++i) {
            int e = tid + 256 * i;
            int r = e >> 4, kk = e & 15;
            int gr = row0 + r, gk = kt + kk;
            float v = 0.f;
            if (gr < M && gk < K) v = A[(size_t)gr * lda + gk];
            As[kk][r] = v;
        }
#pragma unroll
        for (int i = 0; i < 4; ++i) {
            int e = tid + 256 * i;
            int kk = e >> 6, c = e & 63;
            int gk = kt + kk, gc = col0 + c;
            float v = 0.f;
            if (gk < K && gc < N) v = Bm[(size_t)gk * N + gc];
            Bs[kk][c] = v;
        }
        __syncthreads();
#pragma unroll
        for (int kk = 0; kk < 16; ++kk) {
            float a[4], bv[4];
            *(float4*)&a[0]  = *(const float4*)&As[kk][tr * 4];
            *(float4*)&bv[0] = *(const float4*)&Bs[kk][tc * 4];
#pragma unroll
            for (int i = 0; i < 4; ++i)
#pragma unroll
                for (int j = 0; j < 4; ++j) acc[i][j] += a[i] * bv[j];
        }
        __syncthreads();
    }
#pragma unroll
    for (int i = 0; i < 4; ++i) {
        int r = row0 + tr * 4 + i;
        if (r >= M) continue;
#pragma unroll
        for (int j = 0; j < 4; ++j) {
            int c = col0 + tc * 4 + j;
            if (c >= N) continue;
            float v = acc[i][j];
            if (bias) v += bias[c];
            if (leaky) v = v >= 0.f ? v : SLOPE * v;
            Cm[(size_t)r * ldc + c] = v;
        }
    }
}

// ---------- small-M GEMM ----------
__global__ __launch_bounds__(256) void k_sgemm(const float* __restrict__ A, int lda,
                                               const float* __restrict__ Bm,
                                               float* __restrict__ Cm, int ldc,
                                               int N, int K,
                                               const float* __restrict__ bias, int leaky) {
    extern __shared__ float Arow[];
    int r   = blockIdx.x;
    int c0  = blockIdx.y * 256;
    int tid = threadIdx.x;
    for (int k = tid; k < K; k += 256) Arow[k] = A[(size_t)r * lda + k];
    __syncthreads();
    int c = c0 + tid;
    if (c >= N) return;
    float acc = bias ? bias[c] : 0.f;
    for (int k = 0; k < K; ++k) acc += Arow[k] * Bm[(size_t)k * N + c];
    if (leaky) acc = acc >= 0.f ? acc : SLOPE * acc;
    Cm[(size_t)r * ldc + c] = acc;
}

// ---------- gather-max epilogue (+ optional fused row-norm) ----------
__global__ void k_gathermax(const float* __restrict__ Y, int O, int R,
                            const int* __restrict__ idx, int kc,
                            float* __restrict__ out, int ldo, int ooff,
                            float* __restrict__ xxout) {
    extern __shared__ int sidx[];
    __shared__ float red[256];
    int br = blockIdx.x;
    int b  = br / R;
    int o  = threadIdx.x;
    if (o < kc) sidx[o] = idx[(size_t)br * kc + o];
    __syncthreads();
    int O2 = 2 * O;
    float z = Y[(size_t)br * O2 + O + o];
    float best = -FLT_MAX;
    for (int k = 0; k < kc; ++k) {
        int m = sidx[k];
        best = fmaxf(best, Y[(size_t)(b * R + m) * O2 + o]);
    }
    float r = z + best;
    r = r >= 0.f ? r : SLOPE * r;
    out[(size_t)br * ldo + ooff + o] = r;
    if (xxout) {
        red[o] = r * r;
        __syncthreads();
        for (int s = blockDim.x >> 1; s > 0; s >>= 1) {
            if (o < s) red[o] += red[o + s];
            __syncthreads();
        }
        if (o == 0) xxout[br] = red[0];
    }
}

// ---------- channel map ----------
__device__ __forceinline__ void chan_map(int b, int c,
                                         const float* Vf, const float* l1,
                                         const float* l2, const float* l3,
                                         const float*& p, int& st) {
    if (c < 3)        { st = 3;   p = Vf + (size_t)b * N_ * 3   + c; }
    else if (c < 67)  { st = 64;  p = l1 + (size_t)b * N_ * 64  + (c - 3); }
    else if (c < 195) { st = 128; p = l2 + (size_t)b * N_ * 128 + (c - 67); }
    else              { st = 256; p = l3 + (size_t)b * N_ * 256 + (c - 195); }
}

// ---------- pooling phase 1 ----------
__global__ __launch_bounds__(256) void k_pool2(const float* __restrict__ Vf,
                                               const float* __restrict__ l1,
                                               const float* __restrict__ l2,
                                               const float* __restrict__ l3,
                                               const float* __restrict__ W,
                                               float* __restrict__ ppool,
                                               float* __restrict__ psw) {
    __shared__ float Wl[SLABN][J_];
    int blk  = blockIdx.x;
    int b    = blk / NSLAB, slab = blk % NSLAB;
    int n0   = slab * SLABN;
    int tid  = threadIdx.x;

    for (int e = tid; e < J_ * SLABN; e += 256) {
        int j = e / SLABN, n = e % SLABN;
        Wl[n][j] = W[((size_t)b * J_ + j) * N_ + n0 + n];
    }
    __syncthreads();

    if (tid < J_) {
        float s = 0.f;
        for (int n = 0; n < SLABN; ++n) s += Wl[n][tid];
        psw[(size_t)blk * J_ + tid] = s;
    }

    int c0 = tid, c1 = tid + 256;
    const float *p0, *p1 = nullptr; int s0, s1 = 0;
    chan_map(b, c0, Vf, l1, l2, l3, p0, s0);
    bool has1 = (c1 < 451);
    if (has1) chan_map(b, c1, Vf, l1, l2, l3, p1, s1);

    float acc0[J_], acc1[J_];
#pragma unroll
    for (int j = 0; j < J_; ++j) { acc0[j] = 0.f; acc1[j] = 0.f; }

    for (int n = 0; n < SLABN; ++n) {
        float v0 = p0[(size_t)(n0 + n) * s0];
        float v1 = has1 ? p1[(size_t)(n0 + n) * s1] : 0.f;
        const float* wn = &Wl[n][0];
#pragma unroll
        for (int q = 0; q < J_ / 4; ++q) {
            float4 w4 = *(const float4*)(wn + 4 * q);
            acc0[4*q+0] += w4.x * v0;  acc1[4*q+0] += w4.x * v1;
            acc0[4*q+1] += w4.y * v0;  acc1[4*q+1] += w4.y * v1;
            acc0[4*q+2] += w4.z * v0;  acc1[4*q+2] += w4.z * v1;
            acc0[4*q+3] += w4.w * v0;  acc1[4*q+3] += w4.w * v1;
        }
    }
    float* pp = ppool + (size_t)blk * J_ * 451;
#pragma unroll
    for (int j = 0; j < J_; ++j) {
        pp[(size_t)j * 451 + c0] = acc0[j];
        if (has1) pp[(size_t)j * 451 + c1] = acc1[j];
    }
}

// ---------- pooling phase 2 ----------
__global__ __launch_bounds__(256) void k_poolred(const float* __restrict__ ppool,
                                                 const float* __restrict__ psw,
                                                 float* __restrict__ pooled) {
    int bj = blockIdx.x;
    int b  = bj / J_, j = bj % J_;
    int tid = threadIdx.x;

    float sw = 0.f;
    for (int sl = 0; sl < NSLAB; ++sl) sw += psw[(size_t)(b * NSLAB + sl) * J_ + j];
    float inv = 1.f / (sw + 1e-5f);

    for (int c = tid; c < 451; c += 256) {
        float s = 0.f;
        for (int sl = 0; sl < NSLAB; ++sl)
            s += ppool[((size_t)(b * NSLAB + sl) * J_ + j) * 451 + c];
        pooled[(size_t)bj * 451 + c] = s * inv;
    }
}

extern "C" void kernel_launch(void* const* d_in, const int* in_sizes, int n_in,
                              void* d_out, int out_size, void* d_ws, size_t ws_size,
                              hipStream_t stream) {
    const float* V  = (const float*)d_in[0];
    const float* W  = (const float*)d_in[1];
    const int* ringIdx = (const int*)d_in[2];
    const float* g1w = (const float*)d_in[3];
    const float* g1b = (const float*)d_in[4];
    const float* g2w = (const float*)d_in[5];
    const float* g2b = (const float*)d_in[6];
    const float* g3w = (const float*)d_in[7];
    const float* g3b = (const float*)d_in[8];
    const float* s1w = (const float*)d_in[9];
    const float* s1b = (const float*)d_in[10];
    const float* s2w = (const float*)d_in[11];
    const float* s2b = (const float*)d_in[12];
    const float* s3w = (const float*)d_in[13];
    const float* s3b = (const float*)d_in[14];
    const float* m1w = (const float*)d_in[15];
    const float* m1b = (const float*)d_in[16];
    const float* m2w = (const float*)d_in[17];
    const float* m2b = (const float*)d_in[18];
    const float* m3w = (const float*)d_in[19];
    const float* m3b = (const float*)d_in[20];
    (void)n_in; (void)in_sizes; (void)out_size;

    const int szP1 = 3 * 128,    szP2 = 64 * 256,  szP3 = 128 * 512;
    const int szP4 = 451 * 512,  szP5 = 256 * 256, szP6 = 128 * 128;
    const int szP7 = 448 * 512,  szP8 = 512 * 256, szP9 = 256 * 3;

    // D region (floats): nd key-buffers (u16, N*N/2 floats each), must also
    // cover Y (M*512 f32) and the pooling scratch that alias it.
    auto dreg_floats = [&](int nd) -> size_t {
        size_t a = (size_t)nd * ((size_t)N_ * N_ / 2);
        size_t ymax = (size_t)B_ * N_ * 512;                       // 8.39M floats
        size_t pool = (size_t)B_ * NSLAB * J_ * 451 + (size_t)B_ * NSLAB * J_;
        size_t r = a;
        if (ymax > r) r = ymax;
        if (pool > r) r = pool;
        return r;
    };
    auto layout_bytes = [&](int nd) -> size_t {
        size_t f = 0;
        f += (size_t)B_ * N_ * 64 + (size_t)B_ * N_ * 128 + (size_t)B_ * N_ * 256;
        f += (size_t)B_ * N_;                         // xx
        f += dreg_floats(nd);                         // D/Y/pool region
        f += 2 * ((size_t)B_ * N_ * 128 / 2);         // Xhi/Xlo bf16 split buffers
        f += (size_t)B_ * N_ * KNN_;                  // knnIdx (ints)
        f += (size_t)B_ * J_ * 451 + (size_t)B_ * J_ * 448;
        f += (size_t)B_ * J_ * 512 + (size_t)B_ * J_ * 256;
        f += (size_t)(szP1 + szP2 + szP3 + szP4 + szP5 + szP6 + szP7 + szP8 + szP9);
        f += 128 + 256 + 512 + 512 + 256 + 128;
        return f * 4;
    };
    // nb = batches per dist/sel group (deterministic in ws_size -> graph-safe)
    int nb = 1;
    if (ws_size >= layout_bytes(4)) nb = 4;
    else if (ws_size >= layout_bytes(2)) nb = 2;

    // ---- workspace layout (floats) ----
    float* ws = (float*)d_ws;
    size_t off = 0;
    float* l1 = ws + off; off += (size_t)B_ * N_ * 64;
    float* l2 = ws + off; off += (size_t)B_ * N_ * 128;
    float* l3 = ws + off; off += (size_t)B_ * N_ * 256;
    float* xx = ws + off; off += (size_t)B_ * N_;
    float* D  = ws + off; off += dreg_floats(nb);        // keys / Y / pool region
    unsigned short* Dk = (unsigned short*)D;
    float* Y  = D;
    float* ppool = D;
    float* psw   = D + (size_t)B_ * NSLAB * J_ * 451;
    unsigned short* Xhi = (unsigned short*)(ws + off); off += (size_t)B_ * N_ * 128 / 2;
    unsigned short* Xlo = (unsigned short*)(ws + off); off += (size_t)B_ * N_ * 128 / 2;
    int* knnIdx = (int*)(ws + off); off += (size_t)B_ * N_ * KNN_;
    float* pooled = ws + off; off += (size_t)B_ * J_ * 451;
    float* joints = ws + off; off += (size_t)B_ * J_ * 448;
    float* h1 = ws + off; off += (size_t)B_ * J_ * 512;
    float* h2 = ws + off; off += (size_t)B_ * J_ * 256;
    float* P1 = ws + off; off += szP1;
    float* P2 = ws + off; off += szP2;
    float* P3 = ws + off; off += szP3;
    float* P4 = ws + off; off += szP4;
    float* P5 = ws + off; off += szP5;
    float* P6 = ws + off; off += szP6;
    float* P7 = ws + off; off += szP7;
    float* P8 = ws + off; off += szP8;
    float* P9 = ws + off; off += szP9;
    float* bb1 = ws + off; off += 128;
    float* bb2 = ws + off; off += 256;
    float* bb3 = ws + off; off += 512;
    float* bb4 = ws + off; off += 512;
    float* bb5 = ws + off; off += 256;
    float* bb6 = ws + off; off += 128;

    const int M = B_ * N_;   // 16384
    const int MJ = B_ * J_;  // 96
    const int NUTRI = NTILE * (NTILE + 1) / 2;   // 528 upper-tri tiles

    // ---- all weight prep in one launch ----
    k_prepall<<<dim3((szP4 + 255) / 256, 9), 256, 0, stream>>>(
        g1w, g1b, g2w, g2b, g3w, g3b, s1w, s1b, s2w, s2b, s3w, s3b,
        m1w, m2w, m3w, P1, P2, P3, P4, P5, P6, P7, P8, P9,
        bb1, bb2, bb3, bb4, bb5, bb6);

    // ======== geoNet layer 1: C=3 -> O=64 (fused dist+select) ========
    k_norm<<<(M + 255) / 256, 256, 0, stream>>>(V, xx, 3);
    k_selC3<<<dim3(N_, B_), 256, 0, stream>>>(V, xx, knnIdx);
    k_gemm<<<dim3(2, M / 64), 256, 0, stream>>>(V, 3, P1, Y, 128, M, 128, 3, bb1, 0);
    k_gathermax<<<M, 64, KNN_ * sizeof(int), stream>>>(Y, 64, N_, knnIdx, KNN_, l1, 64, 0, xx);

    // ======== layer 2: C=64 -> O=128 ========
    k_split<<<(M * 64 / 4 + 255) / 256, 256, 0, stream>>>(l1, Xhi, Xlo, M * 64 / 4);
    for (int g = 0; g < B_; g += nb) {
        k_dist<<<dim3(NUTRI, nb), 256, 0, stream>>>(Xhi, Xlo, 64, xx, Dk, g);
        k_sel<<<dim3(N_, nb), 256, 0, stream>>>(Dk, l1, 64, xx, knnIdx, g);
    }
    k_gemm<<<dim3(4, M / 64), 256, 0, stream>>>(l1, 64, P2, Y, 256, M, 256, 64, bb2, 0);
    k_gathermax<<<M, 128, KNN_ * sizeof(int), stream>>>(Y, 128, N_, knnIdx, KNN_, l2, 128, 0, xx);

    // ======== layer 3: C=128 -> O=256 ========
    k_split<<<(M * 128 / 4 + 255) / 256, 256, 0, stream>>>(l2, Xhi, Xlo, M * 128 / 4);
    for (int g = 0; g < B_; g += nb) {
        k_dist<<<dim3(NUTRI, nb), 256, 0, stream>>>(Xhi, Xlo, 128, xx, Dk, g);
        k_sel<<<dim3(N_, nb), 256, 0, stream>>>(Dk, l2, 128, xx, knnIdx, g);
    }
    k_gemm<<<dim3(8, M / 64), 256, 0, stream>>>(l2, 128, P3, Y, 512, M, 512, 128, bb3, 0);
    k_gathermax<<<M, 256, KNN_ * sizeof(int), stream>>>(Y, 256, N_, knnIdx, KNN_, l3, 256, 0, nullptr);

    // ======== pooling onto joints ========
    k_pool2<<<B_ * NSLAB, 256, 0, stream>>>(V, l1, l2, l3, W, ppool, psw);
    k_poolred<<<MJ, 256, 0, stream>>>(ppool, psw, pooled);

    // ======== skeleton convs ========
    k_sgemm<<<dim3(MJ, 2), 256, 451 * sizeof(float), stream>>>(pooled, 451, P4, Y, 512, 512, 451, bb4, 0);
    k_gathermax<<<MJ, 256, KR_ * sizeof(int), stream>>>(Y, 256, J_, ringIdx, KR_, joints, 448, 0, nullptr);

    k_sgemm<<<dim3(MJ, 1), 256, 256 * sizeof(float), stream>>>(joints, 448, P5, Y, 256, 256, 256, bb5, 0);
    k_gathermax<<<MJ, 128, KR_ * sizeof(int), stream>>>(Y, 128, J_, ringIdx, KR_, joints, 448, 256, nullptr);

    k_sgemm<<<dim3(MJ, 1), 256, 128 * sizeof(float), stream>>>(joints + 256, 448, P6, Y, 128, 128, 128, bb6, 0);
    k_gathermax<<<MJ, 64, KR_ * sizeof(int), stream>>>(Y, 64, J_, ringIdx, KR_, joints, 448, 384, nullptr);

    // ======== joint MLP ========
    k_sgemm<<<dim3(MJ, 2), 256, 448 * sizeof(float), stream>>>(joints, 448, P7, h1, 512, 512, 448, m1b, 1);
    k_sgemm<<<dim3(MJ, 1), 256, 512 * sizeof(float), stream>>>(h1, 512, P8, h2, 256, 256, 512, m2b, 1);
    k_sgemm<<<dim3(MJ, 1), 256, 256 * sizeof(float), stream>>>(h2, 256, P9, (float*)d_out, 3, 3, 256, m3b, 0);
}

// Round 4
// 890.523 us; speedup vs baseline: 1.4584x; 1.0628x over previous
//
#include <hip/hip_runtime.h>
#include <hip/hip_bf16.h>
#include <float.h>

// Problem constants (from reference setup_inputs)
#define B_   4
#define N_   4096
#define J_   24
#define KR_  4
#define KNN_ 20
#define SLOPE 0.2f
#define SLABN 64             // points per pooling slab
#define NSLAB (N_ / SLABN)   // 64
#define NTILE 32             // 128-wide tiles per dim
#define SCAP 768             // survivor buffer cap
#define KSLACK 8u            // u16-key slack covering split-bf16 error

typedef __attribute__((ext_vector_type(8))) short bf16x8;
typedef __attribute__((ext_vector_type(4))) float f32x4;

// ---------- per-point squared norm ----------
__global__ void k_norm(const float* __restrict__ h, float* __restrict__ xx, int C) {
    int i = blockIdx.x * blockDim.x + threadIdx.x;
    if (i >= B_ * N_) return;
    const float* hp = h + (size_t)i * C;
    float s = 0.f;
    for (int c = 0; c < C; ++c) { float v = hp[c]; s += v * v; }
    xx[i] = s;
}

// ---------- monotone key maps ----------
__device__ __forceinline__ unsigned mapf(float f) {
    unsigned u = __float_as_uint(f);
    return (u & 0x80000000u) ? ~u : (u | 0x80000000u);
}
// top-16 bits of mapf: monotone f32 -> u16 (truncation preserves order)
__device__ __forceinline__ unsigned key16(float f) {
    return mapf(f) >> 16;
}

// ---------- split f32 -> bf16 hi + bf16 lo (both truncated; x = hi + lo + r, |r|<=2^-16|x|) ----------
__global__ void k_split(const float* __restrict__ h, unsigned short* __restrict__ hi,
                        unsigned short* __restrict__ lo, int total4) {
    int i = blockIdx.x * 256 + threadIdx.x;
    if (i >= total4) return;
    float4 v = ((const float4*)h)[i];
    ushort4 h4, l4;
    {
        unsigned u = __float_as_uint(v.x); h4.x = (unsigned short)(u >> 16);
        float r = v.x - __uint_as_float(u & 0xffff0000u); l4.x = (unsigned short)(__float_as_uint(r) >> 16);
    }
    {
        unsigned u = __float_as_uint(v.y); h4.y = (unsigned short)(u >> 16);
        float r = v.y - __uint_as_float(u & 0xffff0000u); l4.y = (unsigned short)(__float_as_uint(r) >> 16);
    }
    {
        unsigned u = __float_as_uint(v.z); h4.z = (unsigned short)(u >> 16);
        float r = v.z - __uint_as_float(u & 0xffff0000u); l4.z = (unsigned short)(__float_as_uint(r) >> 16);
    }
    {
        unsigned u = __float_as_uint(v.w); h4.w = (unsigned short)(u >> 16);
        float r = v.w - __uint_as_float(u & 0xffff0000u); l4.w = (unsigned short)(__float_as_uint(r) >> 16);
    }
    ((ushort4*)hi)[i] = h4;
    ((ushort4*)lo)[i] = l4;
}

// ---------- MFMA distance GEMM (split-bf16, 3-pass) -> u16 keys ----------
// Upper-tri 128x128 tiles; 4 waves, each computing a 64x64 quadrant via
// 4x4 frags of mfma_f32_16x16x32_bf16. Stores are arranged so each 16-lane
// group writes 256 B contiguous (measured: smaller per-group contiguity gets
// 2-3.4x HBM write amplification).
__global__ __launch_bounds__(256) void k_dist(const unsigned short* __restrict__ Hi,
                                              const unsigned short* __restrict__ Lo,
                                              int C,
                                              const float* __restrict__ xxall,
                                              unsigned short* __restrict__ Dall, int b0) {
    __shared__ unsigned short tile[128][136];   // +8 pad: 272B rows, 16B-aligned
    int b = b0 + blockIdx.y;
    const unsigned short* XH = Hi + (size_t)b * N_ * C;
    const unsigned short* XL = Lo + (size_t)b * N_ * C;
    const float* xxb = xxall + (size_t)b * N_;
    unsigned short* D = Dall + (size_t)blockIdx.y * N_ * N_;

    int t = blockIdx.x;                      // linear upper-tri tile id
    int ti = 0;
    while (t >= NTILE - ti) { t -= NTILE - ti; ++ti; }
    int tj = ti + t;
    int row0 = ti * 128, col0 = tj * 128;
    int tid  = threadIdx.x;
    int wv   = tid >> 6, lane = tid & 63;
    int wr   = wv >> 1,  wc   = wv & 1;
    int rbase = row0 + wr * 64;
    int cbase = col0 + wc * 64;
    int lp    = lane & 15;        // point within frag
    int kgrp  = lane >> 4;        // k-group

    f32x4 acc[4][4];
#pragma unroll
    for (int i = 0; i < 4; ++i)
#pragma unroll
        for (int j = 0; j < 4; ++j) acc[i][j] = (f32x4){0.f, 0.f, 0.f, 0.f};

    for (int ks = 0; ks < C; ks += 32) {
        int kb = ks + kgrp * 8;
        bf16x8 ah[4], al[4];
#pragma unroll
        for (int fi = 0; fi < 4; ++fi) {
            size_t ro = (size_t)(rbase + fi * 16 + lp) * C + kb;
            ah[fi] = *(const bf16x8*)(XH + ro);
            al[fi] = *(const bf16x8*)(XL + ro);
        }
#pragma unroll
        for (int fj = 0; fj < 4; ++fj) {
            size_t co = (size_t)(cbase + fj * 16 + lp) * C + kb;
            bf16x8 bh = *(const bf16x8*)(XH + co);
            bf16x8 bl = *(const bf16x8*)(XL + co);
#pragma unroll
            for (int fi = 0; fi < 4; ++fi) {
                acc[fi][fj] = __builtin_amdgcn_mfma_f32_16x16x32_bf16(ah[fi], bh, acc[fi][fj], 0, 0, 0);
                acc[fi][fj] = __builtin_amdgcn_mfma_f32_16x16x32_bf16(ah[fi], bl, acc[fi][fj], 0, 0, 0);
                acc[fi][fj] = __builtin_amdgcn_mfma_f32_16x16x32_bf16(al[fi], bh, acc[fi][fj], 0, 0, 0);
            }
        }
    }

    // epilogue: d = xxr + xxc - 2*dot -> u16 key into LDS tile
    float xxrv = xxb[rbase + lane];
    float xxcv = xxb[cbase + lane];
    int rsub = (lane >> 4) * 4;
#pragma unroll
    for (int fi = 0; fi < 4; ++fi) {
#pragma unroll
        for (int fj = 0; fj < 4; ++fj) {
            float xc = __shfl(xxcv, fj * 16 + lp, 64);
#pragma unroll
            for (int r = 0; r < 4; ++r) {
                float xr = __shfl(xxrv, fi * 16 + rsub + r, 64);
                float d = xr + xc - 2.f * acc[fi][fj][r];
                tile[wr * 64 + fi * 16 + rsub + r][wc * 64 + fj * 16 + lp] =
                    (unsigned short)key16(d);
            }
        }
    }
    __syncthreads();

    // normal store: 16-lane groups each write 256 B contiguous (one full row)
    {
        int r0   = tid >> 4;            // 0..15
        int cseg = (tid & 15) * 8;      // u16 offset; 16 B per lane
#pragma unroll
        for (int q = 0; q < 8; ++q) {
            int row = r0 + q * 16;
            *(uint4*)(D + (size_t)(row0 + row) * N_ + col0 + cseg) =
                *(const uint4*)&tile[row][cseg];
        }
    }
    if (ti == tj) return;
    // mirror store: transpose gather from LDS; 16-lane groups write 256 B contiguous
    {
        int c0g = tid >> 4;             // base column group 0..15
        int g   = tid & 15;             // lane within group -> row segment g*8
#pragma unroll
        for (int cq = 0; cq < 8; ++cq) {
            int c = c0g + cq * 16;
            unsigned short s[8];
#pragma unroll
            for (int q = 0; q < 8; ++q) s[q] = tile[g * 8 + q][c];
            *(uint4*)(D + (size_t)(col0 + c) * N_ + row0 + g * 8) = *(const uint4*)s;
        }
    }
}

// ---------- 64-lane butterfly helpers ----------
__device__ __forceinline__ unsigned long long shflx64(unsigned long long v, int m) {
    unsigned lo = (unsigned)v, hi = (unsigned)(v >> 32);
    lo = (unsigned)__shfl_xor((int)lo, m, 64);
    hi = (unsigned)__shfl_xor((int)hi, m, 64);
    return ((unsigned long long)hi << 32) | lo;
}

// full ascending bitonic sort of one f32 per lane across the wave
__device__ __forceinline__ float bsort64f(float v, int lane) {
#pragma unroll
    for (int k = 2; k <= 64; k <<= 1) {
#pragma unroll
        for (int j = k >> 1; j > 0; j >>= 1) {
            float o = __shfl_xor(v, j, 64);
            bool keepmin = (((lane & j) == 0) == ((lane & k) == 0));
            float mn = fminf(v, o), mx = fmaxf(v, o);
            v = keepmin ? mn : mx;
        }
    }
    return v;
}

// full ascending bitonic sort of one u32 per lane across the wave
__device__ __forceinline__ unsigned bsort64i(unsigned v, int lane) {
#pragma unroll
    for (int k = 2; k <= 64; k <<= 1) {
#pragma unroll
        for (int j = k >> 1; j > 0; j >>= 1) {
            unsigned o = (unsigned)__shfl_xor((int)v, j, 64);
            bool keepmin = (((lane & j) == 0) == ((lane & k) == 0));
            unsigned mn = (v < o) ? v : o;
            unsigned mx = (v < o) ? o : v;
            v = keepmin ? mn : mx;
        }
    }
    return v;
}

// full ascending bitonic sort of one u64 key per lane across the wave
__device__ __forceinline__ unsigned long long bsort64u(unsigned long long v, int lane) {
#pragma unroll
    for (int k = 2; k <= 64; k <<= 1) {
#pragma unroll
        for (int j = k >> 1; j > 0; j >>= 1) {
            unsigned long long o = shflx64(v, j);
            bool keepmin = (((lane & j) == 0) == ((lane & k) == 0));
            bool oless = o < v;
            unsigned long long mn = oless ? o : v;
            unsigned long long mx = oless ? v : o;
            v = keepmin ? mn : mx;
        }
    }
    return v;
}

// ---------- top-20 from u16 key rows: slacked threshold -> exact recompute -> bitonic ----------
// Keys are monotone maps of the split-bf16 approx distance (error delta). With
// tau = (20th of lane-mins, min over waves) and filter key <= tau + KSLACK,
// the survivor set is a superset of the exact top-20 whenever KSLACK covers
// 2*delta in key space (margin here ~1e4x). Survivors' exact f32 distances are
// recomputed from X and ranked by (mapf(d), idx) u64 bitonic -> exact result.
__global__ __launch_bounds__(256) void k_sel(const unsigned short* __restrict__ Dall,
                                             const float* __restrict__ Xall, int C,
                                             const float* __restrict__ xxall,
                                             int* __restrict__ knnIdx, int b0) {
    __shared__ unsigned sidx[SCAP];
    __shared__ unsigned long long skey[SCAP];
    __shared__ float qf[128];
    __shared__ unsigned stau[4];
    __shared__ int scnt;
    int b = b0 + blockIdx.y;
    const unsigned short* Db = Dall + (size_t)blockIdx.y * N_ * N_;
    const float* Xb  = Xall + (size_t)b * N_ * C;
    const float* xxb = xxall + (size_t)b * N_;
    int* idxout = knnIdx + (size_t)b * N_ * KNN_;
    int ql   = blockIdx.x;
    int wv   = threadIdx.x >> 6;
    int lane = threadIdx.x & 63;
    int gbase = wv * 1024 + lane * 16;
    if (threadIdx.x == 0) scnt = 0;
    for (int c = threadIdx.x; c < C; c += 256) qf[c] = Xb[(size_t)ql * C + c];

    const uint4* kp = (const uint4*)(Db + (size_t)ql * N_ + gbase);
    uint4 pa = kp[0], pb = kp[1];
    unsigned kv[16];
    kv[0] = pa.x & 0xffffu;  kv[1] = pa.x >> 16;
    kv[2] = pa.y & 0xffffu;  kv[3] = pa.y >> 16;
    kv[4] = pa.z & 0xffffu;  kv[5] = pa.z >> 16;
    kv[6] = pa.w & 0xffffu;  kv[7] = pa.w >> 16;
    kv[8] = pb.x & 0xffffu;  kv[9] = pb.x >> 16;
    kv[10] = pb.y & 0xffffu; kv[11] = pb.y >> 16;
    kv[12] = pb.z & 0xffffu; kv[13] = pb.z >> 16;
    kv[14] = pb.w & 0xffffu; kv[15] = pb.w >> 16;

    unsigned mn = kv[0];
#pragma unroll
    for (int t = 1; t < 16; ++t) mn = (kv[t] < mn) ? kv[t] : mn;
    mn = bsort64i(mn, lane);
    unsigned tw = (unsigned)__shfl((int)mn, 19, 64);
    if (lane == 0) stau[wv] = tw;
    __syncthreads();
    unsigned tau = stau[0];
    tau = (stau[1] < tau) ? stau[1] : tau;
    tau = (stau[2] < tau) ? stau[2] : tau;
    tau = (stau[3] < tau) ? stau[3] : tau;
    tau += KSLACK;
    if (tau > 0xffffu) tau = 0xffffu;

#pragma unroll
    for (int t = 0; t < 16; ++t) {
        if (kv[t] <= tau) {
            int p = atomicAdd(&scnt, 1);
            if (p < SCAP) sidx[p] = (unsigned)(gbase + t);
        }
    }
    __syncthreads();
    int S = scnt; if (S > SCAP) S = SCAP;
    float xxq = xxb[ql];
    const float4* xq4 = (const float4*)qf;
    for (int s = threadIdx.x; s < S; s += 256) {
        int j = (int)sidx[s];
        const float4* xj = (const float4*)(Xb + (size_t)j * C);
        float a0 = 0.f, a1 = 0.f, a2 = 0.f, a3 = 0.f;
        for (int c4 = 0; c4 < (C >> 2); ++c4) {
            float4 x = xj[c4]; float4 qv = xq4[c4];
            a0 = fmaf(qv.x, x.x, a0);
            a1 = fmaf(qv.y, x.y, a1);
            a2 = fmaf(qv.z, x.z, a2);
            a3 = fmaf(qv.w, x.w, a3);
        }
        float dot = (a0 + a1) + (a2 + a3);
        float d = xxq + xxb[j] - 2.f * dot;
        skey[s] = ((unsigned long long)mapf(d) << 32) | (unsigned)j;
    }
    __syncthreads();
    if (wv != 0) return;
    unsigned long long key = (lane < S) ? skey[lane] : ~0ull;
    key = bsort64u(key, lane);
    for (int consumed = 64; consumed < S; consumed += 44) {
        if (lane >= 20) {
            int src = consumed + lane - 20;
            key = (src < S) ? skey[src] : ~0ull;
        }
        key = bsort64u(key, lane);
    }
    if (lane < KNN_) idxout[ql * KNN_ + lane] = (int)(unsigned)key;
}

// ---------- layer-1 fused dist+select (C=3), exact f32 threshold+compaction ----------
__global__ __launch_bounds__(256) void k_selC3(const float* __restrict__ V,
                                               const float* __restrict__ xx,
                                               int* __restrict__ knnIdx) {
    __shared__ unsigned long long sbuf[SCAP];
    __shared__ float stau[4];
    __shared__ int scnt;
    int b    = blockIdx.y;
    const float* Xb  = V + (size_t)b * N_ * 3;
    const float* xxb = xx + (size_t)b * N_;
    int* idxout = knnIdx + (size_t)b * N_ * KNN_;
    int q    = blockIdx.x;
    int wv   = threadIdx.x >> 6;
    int lane = threadIdx.x & 63;
    int gbase = wv * 1024 + lane * 16;
    if (threadIdx.x == 0) scnt = 0;

    float qx = Xb[q * 3], qy = Xb[q * 3 + 1], qz = Xb[q * 3 + 2];
    float xxq = xxb[q];

    float pts[48];
    const float4* src = (const float4*)(Xb + (size_t)gbase * 3);
#pragma unroll
    for (int t = 0; t < 12; ++t) ((float4*)pts)[t] = src[t];

    float dv[16];
#pragma unroll
    for (int t = 0; t < 16; ++t) {
        float dot = qx * pts[3 * t];
        dot = fmaf(qy, pts[3 * t + 1], dot);
        dot = fmaf(qz, pts[3 * t + 2], dot);
        dv[t] = xxq + xxb[gbase + t] - 2.f * dot;
    }

    float mn = dv[0];
#pragma unroll
    for (int t = 1; t < 16; ++t) mn = fminf(mn, dv[t]);
    mn = bsort64f(mn, lane);
    float tw = __shfl(mn, 19, 64);
    if (lane == 0) stau[wv] = tw;
    __syncthreads();
    float tau = fminf(fminf(stau[0], stau[1]), fminf(stau[2], stau[3]));

#pragma unroll
    for (int t = 0; t < 16; ++t) {
        if (dv[t] <= tau) {
            int p = atomicAdd(&scnt, 1);
            if (p < SCAP)
                sbuf[p] = ((unsigned long long)mapf(dv[t]) << 32) | (unsigned)(gbase + t);
        }
    }
    __syncthreads();
    if (wv != 0) return;
    int S = scnt; if (S > SCAP) S = SCAP;
    unsigned long long key = (lane < S) ? sbuf[lane] : ~0ull;
    key = bsort64u(key, lane);
    for (int consumed = 64; consumed < S; consumed += 44) {
        if (lane >= 20) {
            int srci = consumed + lane - 20;
            key = (srci < S) ? sbuf[srci] : ~0ull;
        }
        key = bsort64u(key, lane);
    }
    if (lane < KNN_) idxout[q * KNN_ + lane] = (int)(unsigned)key;
}

// ---------- fused weight prep ----------
__device__ __forceinline__ void prepP_elem(const float* __restrict__ w,
                                           const float* __restrict__ bias,
                                           int C, int O, float* __restrict__ P,
                                           float* __restrict__ b2, int i) {
    int O2 = 2 * O;
    if (i < O2) b2[i] = (i < O) ? 0.f : bias[i - O];
    if (i >= C * O2) return;
    int k = i / O2, col = i % O2;
    float v;
    if (col < O) v = w[(size_t)col * 2 * C + k];
    else { int o = col - O; v = w[(size_t)o * 2 * C + C + k] - w[(size_t)o * 2 * C + k]; }
    P[i] = v;
}
__device__ __forceinline__ void transp_elem(const float* __restrict__ w, int O, int K,
                                            float* __restrict__ wT, int i) {
    if (i >= O * K) return;
    int k = i / O, o = i % O;
    wT[i] = w[(size_t)o * K + k];
}

__global__ void k_prepall(const float* g1w, const float* g1b,
                          const float* g2w, const float* g2b,
                          const float* g3w, const float* g3b,
                          const float* s1w, const float* s1b,
                          const float* s2w, const float* s2b,
                          const float* s3w, const float* s3b,
                          const float* m1w, const float* m2w, const float* m3w,
                          float* P1, float* P2, float* P3, float* P4, float* P5,
                          float* P6, float* P7, float* P8, float* P9,
                          float* bb1, float* bb2, float* bb3,
                          float* bb4, float* bb5, float* bb6) {
    int i = blockIdx.x * 256 + threadIdx.x;
    switch (blockIdx.y) {
        case 0: prepP_elem(g1w, g1b, 3,   64,  P1, bb1, i); break;
        case 1: prepP_elem(g2w, g2b, 64,  128, P2, bb2, i); break;
        case 2: prepP_elem(g3w, g3b, 128, 256, P3, bb3, i); break;
        case 3: prepP_elem(s1w, s1b, 451, 256, P4, bb4, i); break;
        case 4: prepP_elem(s2w, s2b, 256, 128, P5, bb5, i); break;
        case 5: prepP_elem(s3w, s3b, 128, 64,  P6, bb6, i); break;
        case 6: transp_elem(m1w, 512, 448, P7, i); break;
        case 7: transp_elem(m2w, 256, 512, P8, i); break;
        case 8: transp_elem(m3w, 3,   256, P9, i); break;
    }
}

// ---------- tiled f32 GEMM (large M) ----------
__global__ __launch_bounds__(256) void k_gemm(const float* __restrict__ A, int lda,
                                              const float* __restrict__ Bm,
                                              float* __restrict__ Cm, int ldc,
                                              int M, int N, int K,
                                              const float* __restrict__ bias, int leaky) {
    __shared__ float As[16][68];
    __shared__ float Bs[16][68];
    int tid = threadIdx.x;
    int row0 = blockIdx.y * 64, col0 = blockIdx.x * 64;
    int tr = tid >> 4, tc = tid & 15;
    float acc[4][4] = {{0.f}};
    for (int kt = 0; kt < K; kt += 16) {
#pragma unroll
        for (int i = 0; i < 4; ++i) {
            int e = tid + 256 * i;
            int r = e >> 4, kk = e & 15;
            int gr = row0 + r, gk = kt + kk;
            float v = 0.f;
            if (gr < M && gk < K) v = A[(size_t)gr * lda + gk];
            As[kk][r] = v;
        }
#pragma unroll
        for (int i = 0; i < 4; ++i) {
            int e = tid + 256 * i;
            int kk = e >> 6, c = e & 63;
            int gk = kt + kk, gc = col0 + c;
            float v = 0.f;
            if (gk < K && gc < N) v = Bm[(size_t)gk * N + gc];
            Bs[kk][c] = v;
        }
        __syncthreads();
#pragma unroll
        for (int kk = 0; kk < 16; ++kk) {
            float a[4], bv[4];
            *(float4*)&a[0]  = *(const float4*)&As[kk][tr * 4];
            *(float4*)&bv[0] = *(const float4*)&Bs[kk][tc * 4];
#pragma unroll
            for (int i = 0; i < 4; ++i)
#pragma unroll
                for (int j = 0; j < 4; ++j) acc[i][j] += a[i] * bv[j];
        }
        __syncthreads();
    }
#pragma unroll
    for (int i = 0; i < 4; ++i) {
        int r = row0 + tr * 4 + i;
        if (r >= M) continue;
#pragma unroll
        for (int j = 0; j < 4; ++j) {
            int c = col0 + tc * 4 + j;
            if (c >= N) continue;
            float v = acc[i][j];
            if (bias) v += bias[c];
            if (leaky) v = v >= 0.f ? v : SLOPE * v;
            Cm[(size_t)r * ldc + c] = v;
        }
    }
}

// ---------- small-M GEMM ----------
__global__ __launch_bounds__(256) void k_sgemm(const float* __restrict__ A, int lda,
                                               const float* __restrict__ Bm,
                                               float* __restrict__ Cm, int ldc,
                                               int N, int K,
                                               const float* __restrict__ bias, int leaky) {
    extern __shared__ float Arow[];
    int r   = blockIdx.x;
    int c0  = blockIdx.y * 256;
    int tid = threadIdx.x;
    for (int k = tid; k < K; k += 256) Arow[k] = A[(size_t)r * lda + k];
    __syncthreads();
    int c = c0 + tid;
    if (c >= N) return;
    float acc = bias ? bias[c] : 0.f;
    for (int k = 0; k < K; ++k) acc += Arow[k] * Bm[(size_t)k * N + c];
    if (leaky) acc = acc >= 0.f ? acc : SLOPE * acc;
    Cm[(size_t)r * ldc + c] = acc;
}

// ---------- gather-max epilogue (+ optional fused row-norm) ----------
__global__ void k_gathermax(const float* __restrict__ Y, int O, int R,
                            const int* __restrict__ idx, int kc,
                            float* __restrict__ out, int ldo, int ooff,
                            float* __restrict__ xxout) {
    extern __shared__ int sidx[];
    __shared__ float red[256];
    int br = blockIdx.x;
    int b  = br / R;
    int o  = threadIdx.x;
    if (o < kc) sidx[o] = idx[(size_t)br * kc + o];
    __syncthreads();
    int O2 = 2 * O;
    float z = Y[(size_t)br * O2 + O + o];
    float best = -FLT_MAX;
    for (int k = 0; k < kc; ++k) {
        int m = sidx[k];
        best = fmaxf(best, Y[(size_t)(b * R + m) * O2 + o]);
    }
    float r = z + best;
    r = r >= 0.f ? r : SLOPE * r;
    out[(size_t)br * ldo + ooff + o] = r;
    if (xxout) {
        red[o] = r * r;
        __syncthreads();
        for (int s = blockDim.x >> 1; s > 0; s >>= 1) {
            if (o < s) red[o] += red[o + s];
            __syncthreads();
        }
        if (o == 0) xxout[br] = red[0];
    }
}

// ---------- channel map ----------
__device__ __forceinline__ void chan_map(int b, int c,
                                         const float* Vf, const float* l1,
                                         const float* l2, const float* l3,
                                         const float*& p, int& st) {
    if (c < 3)        { st = 3;   p = Vf + (size_t)b * N_ * 3   + c; }
    else if (c < 67)  { st = 64;  p = l1 + (size_t)b * N_ * 64  + (c - 3); }
    else if (c < 195) { st = 128; p = l2 + (size_t)b * N_ * 128 + (c - 67); }
    else              { st = 256; p = l3 + (size_t)b * N_ * 256 + (c - 195); }
}

// ---------- pooling phase 1 ----------
__global__ __launch_bounds__(256) void k_pool2(const float* __restrict__ Vf,
                                               const float* __restrict__ l1,
                                               const float* __restrict__ l2,
                                               const float* __restrict__ l3,
                                               const float* __restrict__ W,
                                               float* __restrict__ ppool,
                                               float* __restrict__ psw) {
    __shared__ float Wl[SLABN][J_];
    int blk  = blockIdx.x;
    int b    = blk / NSLAB, slab = blk % NSLAB;
    int n0   = slab * SLABN;
    int tid  = threadIdx.x;

    for (int e = tid; e < J_ * SLABN; e += 256) {
        int j = e / SLABN, n = e % SLABN;
        Wl[n][j] = W[((size_t)b * J_ + j) * N_ + n0 + n];
    }
    __syncthreads();

    if (tid < J_) {
        float s = 0.f;
        for (int n = 0; n < SLABN; ++n) s += Wl[n][tid];
        psw[(size_t)blk * J_ + tid] = s;
    }

    int c0 = tid, c1 = tid + 256;
    const float *p0, *p1 = nullptr; int s0, s1 = 0;
    chan_map(b, c0, Vf, l1, l2, l3, p0, s0);
    bool has1 = (c1 < 451);
    if (has1) chan_map(b, c1, Vf, l1, l2, l3, p1, s1);

    float acc0[J_], acc1[J_];
#pragma unroll
    for (int j = 0; j < J_; ++j) { acc0[j] = 0.f; acc1[j] = 0.f; }

    for (int n = 0; n < SLABN; ++n) {
        float v0 = p0[(size_t)(n0 + n) * s0];
        float v1 = has1 ? p1[(size_t)(n0 + n) * s1] : 0.f;
        const float* wn = &Wl[n][0];
#pragma unroll
        for (int q = 0; q < J_ / 4; ++q) {
            float4 w4 = *(const float4*)(wn + 4 * q);
            acc0[4*q+0] += w4.x * v0;  acc1[4*q+0] += w4.x * v1;
            acc0[4*q+1] += w4.y * v0;  acc1[4*q+1] += w4.y * v1;
            acc0[4*q+2] += w4.z * v0;  acc1[4*q+2] += w4.z * v1;
            acc0[4*q+3] += w4.w * v0;  acc1[4*q+3] += w4.w * v1;
        }
    }
    float* pp = ppool + (size_t)blk * J_ * 451;
#pragma unroll
    for (int j = 0; j < J_; ++j) {
        pp[(size_t)j * 451 + c0] = acc0[j];
        if (has1) pp[(size_t)j * 451 + c1] = acc1[j];
    }
}

// ---------- pooling phase 2 ----------
__global__ __launch_bounds__(256) void k_poolred(const float* __restrict__ ppool,
                                                 const float* __restrict__ psw,
                                                 float* __restrict__ pooled) {
    int bj = blockIdx.x;
    int b  = bj / J_, j = bj % J_;
    int tid = threadIdx.x;

    float sw = 0.f;
    for (int sl = 0; sl < NSLAB; ++sl) sw += psw[(size_t)(b * NSLAB + sl) * J_ + j];
    float inv = 1.f / (sw + 1e-5f);

    for (int c = tid; c < 451; c += 256) {
        float s = 0.f;
        for (int sl = 0; sl < NSLAB; ++sl)
            s += ppool[((size_t)(b * NSLAB + sl) * J_ + j) * 451 + c];
        pooled[(size_t)bj * 451 + c] = s * inv;
    }
}

extern "C" void kernel_launch(void* const* d_in, const int* in_sizes, int n_in,
                              void* d_out, int out_size, void* d_ws, size_t ws_size,
                              hipStream_t stream) {
    const float* V  = (const float*)d_in[0];
    const float* W  = (const float*)d_in[1];
    const int* ringIdx = (const int*)d_in[2];
    const float* g1w = (const float*)d_in[3];
    const float* g1b = (const float*)d_in[4];
    const float* g2w = (const float*)d_in[5];
    const float* g2b = (const float*)d_in[6];
    const float* g3w = (const float*)d_in[7];
    const float* g3b = (const float*)d_in[8];
    const float* s1w = (const float*)d_in[9];
    const float* s1b = (const float*)d_in[10];
    const float* s2w = (const float*)d_in[11];
    const float* s2b = (const float*)d_in[12];
    const float* s3w = (const float*)d_in[13];
    const float* s3b = (const float*)d_in[14];
    const float* m1w = (const float*)d_in[15];
    const float* m1b = (const float*)d_in[16];
    const float* m2w = (const float*)d_in[17];
    const float* m2b = (const float*)d_in[18];
    const float* m3w = (const float*)d_in[19];
    const float* m3b = (const float*)d_in[20];
    (void)n_in; (void)in_sizes; (void)out_size;

    const int szP1 = 3 * 128,    szP2 = 64 * 256,  szP3 = 128 * 512;
    const int szP4 = 451 * 512,  szP5 = 256 * 256, szP6 = 128 * 128;
    const int szP7 = 448 * 512,  szP8 = 512 * 256, szP9 = 256 * 3;

    // D region (floats): nd key-buffers (u16, N*N/2 floats each), must also
    // cover Y (M*512 f32) and the pooling scratch that alias it.
    auto dreg_floats = [&](int nd) -> size_t {
        size_t a = (size_t)nd * ((size_t)N_ * N_ / 2);
        size_t ymax = (size_t)B_ * N_ * 512;                       // 8.39M floats
        size_t pool = (size_t)B_ * NSLAB * J_ * 451 + (size_t)B_ * NSLAB * J_;
        size_t r = a;
        if (ymax > r) r = ymax;
        if (pool > r) r = pool;
        return r;
    };
    auto layout_bytes = [&](int nd) -> size_t {
        size_t f = 0;
        f += (size_t)B_ * N_ * 64 + (size_t)B_ * N_ * 128 + (size_t)B_ * N_ * 256;
        f += (size_t)B_ * N_;                         // xx
        f += dreg_floats(nd);                         // D/Y/pool region
        f += 2 * ((size_t)B_ * N_ * 128 / 2);         // Xhi/Xlo bf16 split buffers
        f += (size_t)B_ * N_ * KNN_;                  // knnIdx (ints)
        f += (size_t)B_ * J_ * 451 + (size_t)B_ * J_ * 448;
        f += (size_t)B_ * J_ * 512 + (size_t)B_ * J_ * 256;
        f += (size_t)(szP1 + szP2 + szP3 + szP4 + szP5 + szP6 + szP7 + szP8 + szP9);
        f += 128 + 256 + 512 + 512 + 256 + 128;
        return f * 4;
    };
    // nb = batches per dist/sel group (deterministic in ws_size -> graph-safe)
    int nb = 1;
    if (ws_size >= layout_bytes(4)) nb = 4;
    else if (ws_size >= layout_bytes(2)) nb = 2;

    // ---- workspace layout (floats) ----
    float* ws = (float*)d_ws;
    size_t off = 0;
    float* l1 = ws + off; off += (size_t)B_ * N_ * 64;
    float* l2 = ws + off; off += (size_t)B_ * N_ * 128;
    float* l3 = ws + off; off += (size_t)B_ * N_ * 256;
    float* xx = ws + off; off += (size_t)B_ * N_;
    float* D  = ws + off; off += dreg_floats(nb);        // keys / Y / pool region
    unsigned short* Dk = (unsigned short*)D;
    float* Y  = D;
    float* ppool = D;
    float* psw   = D + (size_t)B_ * NSLAB * J_ * 451;
    unsigned short* Xhi = (unsigned short*)(ws + off); off += (size_t)B_ * N_ * 128 / 2;
    unsigned short* Xlo = (unsigned short*)(ws + off); off += (size_t)B_ * N_ * 128 / 2;
    int* knnIdx = (int*)(ws + off); off += (size_t)B_ * N_ * KNN_;
    float* pooled = ws + off; off += (size_t)B_ * J_ * 451;
    float* joints = ws + off; off += (size_t)B_ * J_ * 448;
    float* h1 = ws + off; off += (size_t)B_ * J_ * 512;
    float* h2 = ws + off; off += (size_t)B_ * J_ * 256;
    float* P1 = ws + off; off += szP1;
    float* P2 = ws + off; off += szP2;
    float* P3 = ws + off; off += szP3;
    float* P4 = ws + off; off += szP4;
    float* P5 = ws + off; off += szP5;
    float* P6 = ws + off; off += szP6;
    float* P7 = ws + off; off += szP7;
    float* P8 = ws + off; off += szP8;
    float* P9 = ws + off; off += szP9;
    float* bb1 = ws + off; off += 128;
    float* bb2 = ws + off; off += 256;
    float* bb3 = ws + off; off += 512;
    float* bb4 = ws + off; off += 512;
    float* bb5 = ws + off; off += 256;
    float* bb6 = ws + off; off += 128;

    const int M = B_ * N_;   // 16384
    const int MJ = B_ * J_;  // 96
    const int NUTRI = NTILE * (NTILE + 1) / 2;   // 528 upper-tri tiles

    // ---- all weight prep in one launch ----
    k_prepall<<<dim3((szP4 + 255) / 256, 9), 256, 0, stream>>>(
        g1w, g1b, g2w, g2b, g3w, g3b, s1w, s1b, s2w, s2b, s3w, s3b,
        m1w, m2w, m3w, P1, P2, P3, P4, P5, P6, P7, P8, P9,
        bb1, bb2, bb3, bb4, bb5, bb6);

    // ======== geoNet layer 1: C=3 -> O=64 (fused dist+select) ========
    k_norm<<<(M + 255) / 256, 256, 0, stream>>>(V, xx, 3);
    k_selC3<<<dim3(N_, B_), 256, 0, stream>>>(V, xx, knnIdx);
    k_gemm<<<dim3(2, M / 64), 256, 0, stream>>>(V, 3, P1, Y, 128, M, 128, 3, bb1, 0);
    k_gathermax<<<M, 64, KNN_ * sizeof(int), stream>>>(Y, 64, N_, knnIdx, KNN_, l1, 64, 0, xx);

    // ======== layer 2: C=64 -> O=128 ========
    k_split<<<(M * 64 / 4 + 255) / 256, 256, 0, stream>>>(l1, Xhi, Xlo, M * 64 / 4);
    for (int g = 0; g < B_; g += nb) {
        k_dist<<<dim3(NUTRI, nb), 256, 0, stream>>>(Xhi, Xlo, 64, xx, Dk, g);
        k_sel<<<dim3(N_, nb), 256, 0, stream>>>(Dk, l1, 64, xx, knnIdx, g);
    }
    k_gemm<<<dim3(4, M / 64), 256, 0, stream>>>(l1, 64, P2, Y, 256, M, 256, 64, bb2, 0);
    k_gathermax<<<M, 128, KNN_ * sizeof(int), stream>>>(Y, 128, N_, knnIdx, KNN_, l2, 128, 0, xx);

    // ======== layer 3: C=128 -> O=256 ========
    k_split<<<(M * 128 / 4 + 255) / 256, 256, 0, stream>>>(l2, Xhi, Xlo, M * 128 / 4);
    for (int g = 0; g < B_; g += nb) {
        k_dist<<<dim3(NUTRI, nb), 256, 0, stream>>>(Xhi, Xlo, 128, xx, Dk, g);
        k_sel<<<dim3(N_, nb), 256, 0, stream>>>(Dk, l2, 128, xx, knnIdx, g);
    }
    k_gemm<<<dim3(8, M / 64), 256, 0, stream>>>(l2, 128, P3, Y, 512, M, 512, 128, bb3, 0);
    k_gathermax<<<M, 256, KNN_ * sizeof(int), stream>>>(Y, 256, N_, knnIdx, KNN_, l3, 256, 0, nullptr);

    // ======== pooling onto joints ========
    k_pool2<<<B_ * NSLAB, 256, 0, stream>>>(V, l1, l2, l3, W, ppool, psw);
    k_poolred<<<MJ, 256, 0, stream>>>(ppool, psw, pooled);

    // ======== skeleton convs ========
    k_sgemm<<<dim3(MJ, 2), 256, 451 * sizeof(float), stream>>>(pooled, 451, P4, Y, 512, 512, 451, bb4, 0);
    k_gathermax<<<MJ, 256, KR_ * sizeof(int), stream>>>(Y, 256, J_, ringIdx, KR_, joints, 448, 0, nullptr);

    k_sgemm<<<dim3(MJ, 1), 256, 256 * sizeof(float), stream>>>(joints, 448, P5, Y, 256, 256, 256, bb5, 0);
    k_gathermax<<<MJ, 128, KR_ * sizeof(int), stream>>>(Y, 128, J_, ringIdx, KR_, joints, 448, 256, nullptr);

    k_sgemm<<<dim3(MJ, 1), 256, 128 * sizeof(float), stream>>>(joints + 256, 448, P6, Y, 128, 128, 128, bb6, 0);
    k_gathermax<<<MJ, 64, KR_ * sizeof(int), stream>>>(Y, 64, J_, ringIdx, KR_, joints, 448, 384, nullptr);

    // ======== joint MLP ========
    k_sgemm<<<dim3(MJ, 2), 256, 448 * sizeof(float), stream>>>(joints, 448, P7, h1, 512, 512, 448, m1b, 1);
    k_sgemm<<<dim3(MJ, 1), 256, 512 * sizeof(float), stream>>>(h1, 512, P8, h2, 256, 256, 512, m2b, 1);
    k_sgemm<<<dim3(MJ, 1), 256, 256 * sizeof(float), stream>>>(h2, 256, P9, (float*)d_out, 3, 3, 256, m3b, 0);
}